// Round 1
// 454.557 us; speedup vs baseline: 1.0090x; 1.0090x over previous
//
#include <hip/hip_runtime.h>
#include <math.h>

#define HEADS 4
#define HD 32
#define DIM 128
#define NEG_SLOPE 0.2f
#define EPS_SM 1e-8f
#define EPS_LN 1e-5f
#define GROWS 64
#define SH1 9              // 512 segments per coarse bin; NBIN = ceil(2N/512) <= 512
#define PB 128             // partition blocks

typedef _Float16 h2_t __attribute__((ext_vector_type(2)));

__device__ __forceinline__ float lrelu(float x) { return x > 0.f ? x : NEG_SLOPE * x; }
__device__ __forceinline__ unsigned pkh(float a, float b) {
    return __builtin_bit_cast(unsigned, __builtin_amdgcn_cvt_pkrtz(a, b));
}
__device__ __forceinline__ float dot2(unsigned a, unsigned b, float c) {
    return __builtin_amdgcn_fdot2(__builtin_bit_cast(h2_t, a), __builtin_bit_cast(h2_t, b), c, false);
}

template<int LIM> __device__ __forceinline__ void rmax4(float& a, float& b, float& c, float& d) {
#pragma unroll
    for (int s = 1; s < LIM; s <<= 1) {
        a = fmaxf(a, __shfl_xor(a, s, 64));
        b = fmaxf(b, __shfl_xor(b, s, 64));
        c = fmaxf(c, __shfl_xor(c, s, 64));
        d = fmaxf(d, __shfl_xor(d, s, 64));
    }
}
template<int LIM> __device__ __forceinline__ void rsum4(float& a, float& b, float& c, float& d) {
#pragma unroll
    for (int s = 1; s < LIM; s <<= 1) {
        a += __shfl_xor(a, s, 64);
        b += __shfl_xor(b, s, 64);
        c += __shfl_xor(c, s, 64);
        d += __shfl_xor(d, s, 64);
    }
}

// ---------------- fused dual GEMM + attention dots + f16 pack ----------------
__global__ __launch_bounds__(256) void dual_gemm_k(const float* __restrict__ h,
                                                   const float* __restrict__ W,
                                                   const float* __restrict__ V,
                                                   const float* __restrict__ a_in,
                                                   const float* __restrict__ a_out,
                                                   float* __restrict__ h_self,
                                                   unsigned* __restrict__ hp_pk,
                                                   float* __restrict__ pA0, float* __restrict__ pA1,
                                                   float* __restrict__ pB0, float* __restrict__ pB1,
                                                   int N) {
    __shared__ float As[32][GROWS];
    __shared__ float Ws[32][DIM];
    __shared__ float Vs[32][DIM];
    __shared__ float ainL[256], aoutL[256];
    const int tid = threadIdx.x;
    const int cg = tid & 15;
    const int rg = tid >> 4;
    const int row0 = blockIdx.x * GROWS;

    ainL[tid] = a_in[tid];
    aoutL[tid] = a_out[tid];

    float accP[4][8], accS[4][8];
#pragma unroll
    for (int r = 0; r < 4; ++r)
#pragma unroll
        for (int c = 0; c < 8; ++c) { accP[r][c] = 0.f; accS[r][c] = 0.f; }

    for (int kc = 0; kc < 4; ++kc) {
        __syncthreads();
#pragma unroll
        for (int p = 0; p < 2; ++p) {
            int f = tid + p * 256;
            int r = f >> 3, c4 = f & 7;
            float4 v = make_float4(0.f, 0.f, 0.f, 0.f);
            if (row0 + r < N) v = ((const float4*)h)[(size_t)(row0 + r) * 32 + kc * 8 + c4];
            As[c4 * 4 + 0][r] = v.x;
            As[c4 * 4 + 1][r] = v.y;
            As[c4 * 4 + 2][r] = v.z;
            As[c4 * 4 + 3][r] = v.w;
        }
#pragma unroll
        for (int p = 0; p < 4; ++p) {
            int f = tid + p * 256;
            int lk = f >> 5, c4 = f & 31;
            ((float4*)&Ws[lk][0])[c4] = ((const float4*)W)[(size_t)(kc * 32 + lk) * 32 + c4];
            ((float4*)&Vs[lk][0])[c4] = ((const float4*)V)[(size_t)(kc * 32 + lk) * 32 + c4];
        }
        __syncthreads();
#pragma unroll
        for (int kk = 0; kk < 32; ++kk) {
            float4 a = *(const float4*)&As[kk][rg * 4];
            float4 w0 = *(const float4*)&Ws[kk][cg * 8];
            float4 w1 = *(const float4*)&Ws[kk][cg * 8 + 4];
            float4 v0 = *(const float4*)&Vs[kk][cg * 8];
            float4 v1 = *(const float4*)&Vs[kk][cg * 8 + 4];
            float av[4] = {a.x, a.y, a.z, a.w};
            float wv[8] = {w0.x, w0.y, w0.z, w0.w, w1.x, w1.y, w1.z, w1.w};
            float vv[8] = {v0.x, v0.y, v0.z, v0.w, v1.x, v1.y, v1.z, v1.w};
#pragma unroll
            for (int r = 0; r < 4; ++r)
#pragma unroll
                for (int c = 0; c < 8; ++c) {
                    accP[r][c] += av[r] * wv[c];
                    accS[r][c] += av[r] * vv[c];
                }
        }
    }

    // ---- epilogue 1: h_self (f32) ----
#pragma unroll
    for (int r = 0; r < 4; ++r) {
        int row = row0 + rg * 4 + r;
        if (row < N) {
            float4 s0 = make_float4(accS[r][0], accS[r][1], accS[r][2], accS[r][3]);
            float4 s1 = make_float4(accS[r][4], accS[r][5], accS[r][6], accS[r][7]);
            ((float4*)h_self)[(size_t)row * 32 + cg * 2] = s0;
            ((float4*)h_self)[(size_t)row * 32 + cg * 2 + 1] = s1;
        }
    }

    // ---- epilogue 2: attention dot tables ----
    const int head = cg >> 2, qi = cg & 3;
#pragma unroll
    for (int r = 0; r < 4; ++r) {
        float d0 = 0.f, d1 = 0.f, d2 = 0.f, d3 = 0.f;
#pragma unroll
        for (int c = 0; c < 8; ++c) {
            float v = accP[r][c];
            int k = head * 64 + qi * 8 + c;
            d0 += v * ainL[k];
            d1 += v * ainL[k + 32];
            d2 += v * aoutL[k];
            d3 += v * aoutL[k + 32];
        }
        d0 += __shfl_xor(d0, 1, 64); d0 += __shfl_xor(d0, 2, 64);
        d1 += __shfl_xor(d1, 1, 64); d1 += __shfl_xor(d1, 2, 64);
        d2 += __shfl_xor(d2, 1, 64); d2 += __shfl_xor(d2, 2, 64);
        d3 += __shfl_xor(d3, 1, 64); d3 += __shfl_xor(d3, 2, 64);
        if (qi == 0) {
            int row = row0 + rg * 4 + r;
            if (row < N) {
                pA0[row * 4 + head] = d0;
                pA1[row * 4 + head] = d1;
                pB0[row * 4 + head] = d2;
                pB1[row * 4 + head] = d3;
            }
        }
    }

    // ---- epilogue 3: plain f16 row pack (channels cg*8..cg*8+7), no LDS exchange ----
#pragma unroll
    for (int r = 0; r < 4; ++r) {
        int row = row0 + rg * 4 + r;
        if (row < N) {
            uint4 pk;
            pk.x = pkh(accP[r][0], accP[r][1]);
            pk.y = pkh(accP[r][2], accP[r][3]);
            pk.z = pkh(accP[r][4], accP[r][5]);
            pk.w = pkh(accP[r][6], accP[r][7]);
            ((uint4*)hp_pk)[(size_t)row * 16 + cg] = pk;
        }
    }
}

// ---------------- deterministic two-level CSR build (no global atomics) ----------------
__global__ __launch_bounds__(256) void part1a_k(const int* __restrict__ ei, int* __restrict__ cntmat,
                                                int E, int N, int NBIN) {
    __shared__ int lcnt[512];
    const int t = threadIdx.x;
    const int CH = (E + gridDim.x - 1) / gridDim.x;
    const int e0 = blockIdx.x * CH;
    const int e1 = min(e0 + CH, E);
    for (int i = t; i < 512; i += 256) lcnt[i] = 0;
    __syncthreads();
    for (int e = e0 + t; e < e1; e += 256) {
        int s = ei[e], d = ei[E + e];
        atomicAdd(&lcnt[d >> SH1], 1);
        atomicAdd(&lcnt[(N + s) >> SH1], 1);
    }
    __syncthreads();
    for (int i = t; i < NBIN; i += 256) cntmat[i * PB + blockIdx.x] = lcnt[i];
}

__global__ __launch_bounds__(128) void scanB_k(const int* __restrict__ cntmat,
                                               int* __restrict__ blkoff, int* __restrict__ btot) {
    __shared__ int ls[PB];
    const int bin = blockIdx.x;
    const int t = threadIdx.x;
    int v = cntmat[bin * PB + t];
    ls[t] = v;
    __syncthreads();
#pragma unroll
    for (int d = 1; d < PB; d <<= 1) {
        int u = (t >= d) ? ls[t - d] : 0;
        __syncthreads();
        ls[t] += u;
        __syncthreads();
    }
    blkoff[bin * PB + t] = ls[t] - v;
    if (t == PB - 1) btot[bin] = ls[t];
}

__global__ __launch_bounds__(256) void scanC_k(const int* __restrict__ btot,
                                               int* __restrict__ bbase, int NBIN, int twoE) {
    __shared__ int ls[256];
    int t = threadIdx.x;
    int i0 = 2 * t, i1 = 2 * t + 1;
    int v0 = (i0 < NBIN) ? btot[i0] : 0;
    int v1 = (i1 < NBIN) ? btot[i1] : 0;
    int pair = v0 + v1;
    ls[t] = pair;
    __syncthreads();
#pragma unroll
    for (int d = 1; d < 256; d <<= 1) {
        int u = (t >= d) ? ls[t - d] : 0;
        __syncthreads();
        ls[t] += u;
        __syncthreads();
    }
    int excl = ls[t] - pair;
    if (i0 < NBIN) bbase[i0] = excl;
    if (i1 < NBIN) bbase[i1] = excl + v0;
    if (t == 0) bbase[NBIN] = twoE;
}

__global__ __launch_bounds__(256) void part1b_k(const int* __restrict__ ei,
                                                const int* __restrict__ bbase,
                                                const int* __restrict__ blkoff,
                                                unsigned* __restrict__ rec, int E, int N, int NBIN) {
    __shared__ int gb[512];
    __shared__ int lcur[512];
    const int t = threadIdx.x;
    const int CH = (E + gridDim.x - 1) / gridDim.x;
    const int e0 = blockIdx.x * CH;
    const int e1 = min(e0 + CH, E);
    for (int i = t; i < 512; i += 256) lcur[i] = 0;
    for (int i = t; i < NBIN; i += 256) gb[i] = bbase[i] + blkoff[i * PB + blockIdx.x];
    __syncthreads();
    for (int e = e0 + t; e < e1; e += 256) {
        int s = ei[e], d = ei[E + e];
        int b1 = d >> SH1;
        int r1 = atomicAdd(&lcur[b1], 1);
        rec[gb[b1] + r1] = (unsigned)s | ((unsigned)(d & 511) << 20);
        int so = N + s;
        int b2 = so >> SH1;
        int r2 = atomicAdd(&lcur[b2], 1);
        rec[gb[b2] + r2] = (unsigned)d | ((unsigned)(so & 511) << 20);
    }
}

__global__ __launch_bounds__(256) void build2_k(const unsigned* __restrict__ rec,
                                                const int* __restrict__ bbase,
                                                int* __restrict__ off, int* __restrict__ csr,
                                                int M, int twoE, int NBIN) {
    __shared__ int lcnt[512];
    __shared__ int lcur[512];
    __shared__ int ls[256];
    const int b = blockIdx.x;
    const int t = threadIdx.x;
    const int base = bbase[b];
    const int cnt = bbase[b + 1] - base;
    const int seg0 = b << SH1;
    for (int i = t; i < 512; i += 256) lcnt[i] = 0;
    __syncthreads();
    for (int k = t; k < cnt; k += 256) atomicAdd(&lcnt[rec[base + k] >> 20], 1);
    __syncthreads();
    int v0 = lcnt[2 * t], v1 = lcnt[2 * t + 1];
    int pair = v0 + v1;
    ls[t] = pair;
    __syncthreads();
#pragma unroll
    for (int d = 1; d < 256; d <<= 1) {
        int u = (t >= d) ? ls[t - d] : 0;
        __syncthreads();
        ls[t] += u;
        __syncthreads();
    }
    int excl = ls[t] - pair;
    lcur[2 * t] = excl;
    lcur[2 * t + 1] = excl + v0;
    int sg = seg0 + 2 * t;
    if (sg < M) off[sg] = base + excl;
    if (sg + 1 < M) off[sg + 1] = base + excl + v0;
    if (b == NBIN - 1 && t == 0) off[M] = twoE;
    __syncthreads();
    for (int k = t; k < cnt; k += 256) {
        unsigned r = rec[base + k];
        int pos = atomicAdd(&lcur[r >> 20], 1);
        csr[base + pos] = (int)(r & 0xFFFFFu);
    }
}

// ---------------- fused: per-node softmax-aggregate + combine + LN ----------------
// hp rows are plain f16[128]. Quarter-wave handles 2 edges/iter: per packed word
// (2c,2c+1) of rows A,B, v_perm builds (A_c,B_c) and v_dot2_f32_f16 does both MACs.
__global__ __launch_bounds__(256) void node_aggr_ln_k(const unsigned* __restrict__ hp_pk,
                                                      const float* __restrict__ h_self,
                                                      const float* __restrict__ pA0, const float* __restrict__ pA1,
                                                      const float* __restrict__ pB0, const float* __restrict__ pB1,
                                                      const int* __restrict__ off, const int* __restrict__ csr,
                                                      const float* __restrict__ bias,
                                                      const float* __restrict__ gamma,
                                                      const float* __restrict__ beta,
                                                      float* __restrict__ out, int N) {
    __shared__ int sds[4][64];     // per-edge sender id
    __shared__ uint2 wts[4][64];   // per-edge f16 head weights: {pk(w0,w1), pk(w2,w3)}
    const int wave = threadIdx.x >> 6;
    const int lane = threadIdx.x & 63;
    const int n = blockIdx.x * 4 + wave;
    if (n >= N) return;
    const int l15 = lane & 15;
    const int q = lane >> 4;
    // lane covers channels 8*l15..8*l15+7, all in head l15>>2
    const unsigned wsel = (l15 & 4) ? 0x07060302u : 0x05040100u;  // pick f16 (h&1) of weight words
    const bool hlo = (l15 < 8);                                   // head < 2
    int* sdw = sds[wave];
    uint2* wtw = wts[wave];
    const char* hpb = (const char*)hp_pk;   // row stride 256 B
    const unsigned rowoff = (unsigned)l15 << 4;

    float acc[8];
#pragma unroll
    for (int k = 0; k < 8; ++k) acc[k] = 0.f;

#pragma unroll
    for (int dir = 0; dir < 2; ++dir) {
        const int seg = (dir == 0) ? n : N + n;
        const int beg = off[seg], end = off[seg + 1];
        const int len = end - beg;
        if (len == 0) continue;
        const float* __restrict__ p0 = (dir == 0) ? pA0 : pB0;
        const float* __restrict__ p1 = (dir == 0) ? pA1 : pB1;
        float4 r1 = ((const float4*)p1)[n];

        if (len <= 64) {
            int sid = 0;
            float e0 = -INFINITY, e1 = -INFINITY, e2 = -INFINITY, e3 = -INFINITY;
            if (lane < len) {
                sid = csr[beg + lane];
                float4 r0 = ((const float4*)p0)[sid];
                e0 = lrelu(r0.x + r1.x);
                e1 = lrelu(r0.y + r1.y);
                e2 = lrelu(r0.z + r1.z);
                e3 = lrelu(r0.w + r1.w);
            }
            float m0 = e0, m1 = e1, m2 = e2, m3 = e3;
            if (len <= 16)      rmax4<16>(m0, m1, m2, m3);
            else if (len <= 32) rmax4<32>(m0, m1, m2, m3);
            else                rmax4<64>(m0, m1, m2, m3);
            float w0 = 0.f, w1 = 0.f, w2 = 0.f, w3 = 0.f;
            if (lane < len) {
                w0 = __expf(e0 - m0); w1 = __expf(e1 - m1);
                w2 = __expf(e2 - m2); w3 = __expf(e3 - m3);
            }
            float s0 = w0, s1 = w1, s2 = w2, s3 = w3;
            if (len <= 16)      rsum4<16>(s0, s1, s2, s3);
            else if (len <= 32) rsum4<32>(s0, s1, s2, s3);
            else                rsum4<64>(s0, s1, s2, s3);
            w0 *= 1.f / (s0 + EPS_SM);
            w1 *= 1.f / (s1 + EPS_SM);
            w2 *= 1.f / (s2 + EPS_SM);
            w3 *= 1.f / (s3 + EPS_SM);
            sdw[lane] = sid;
            wtw[lane] = make_uint2(pkh(w0, w1), pkh(w2, w3));
            const int npair = (len + 7) >> 3;   // 8 edges (4 pairs) per iter
#pragma unroll 2
            for (int t = 0; t < npair; ++t) {
                int pi = 4 * t + q;
                uint2 sp = *(const uint2*)&sdw[2 * pi];
                uint4 wp = *(const uint4*)&wtw[2 * pi];
                uint4 u = *(const uint4*)(hpb + (((unsigned)sp.x << 8) + rowoff));
                uint4 v = *(const uint4*)(hpb + (((unsigned)sp.y << 8) + rowoff));
                unsigned wA = hlo ? wp.x : wp.y;
                unsigned wB = hlo ? wp.z : wp.w;
                unsigned wpk = __builtin_amdgcn_perm(wB, wA, wsel);
                acc[0] = dot2(__builtin_amdgcn_perm(v.x, u.x, 0x05040100u), wpk, acc[0]);
                acc[1] = dot2(__builtin_amdgcn_perm(v.x, u.x, 0x07060302u), wpk, acc[1]);
                acc[2] = dot2(__builtin_amdgcn_perm(v.y, u.y, 0x05040100u), wpk, acc[2]);
                acc[3] = dot2(__builtin_amdgcn_perm(v.y, u.y, 0x07060302u), wpk, acc[3]);
                acc[4] = dot2(__builtin_amdgcn_perm(v.z, u.z, 0x05040100u), wpk, acc[4]);
                acc[5] = dot2(__builtin_amdgcn_perm(v.z, u.z, 0x07060302u), wpk, acc[5]);
                acc[6] = dot2(__builtin_amdgcn_perm(v.w, u.w, 0x05040100u), wpk, acc[6]);
                acc[7] = dot2(__builtin_amdgcn_perm(v.w, u.w, 0x07060302u), wpk, acc[7]);
            }
        } else {
            // rare: deg > 64 — 2 reduction passes, then chunked
            float m0 = -INFINITY, m1 = -INFINITY, m2 = -INFINITY, m3 = -INFINITY;
            for (int base = beg; base < end; base += 64) {
                int j = base + lane;
                if (j < end) {
                    int sid = csr[j];
                    float4 r0 = ((const float4*)p0)[sid];
                    m0 = fmaxf(m0, lrelu(r0.x + r1.x));
                    m1 = fmaxf(m1, lrelu(r0.y + r1.y));
                    m2 = fmaxf(m2, lrelu(r0.z + r1.z));
                    m3 = fmaxf(m3, lrelu(r0.w + r1.w));
                }
            }
            rmax4<64>(m0, m1, m2, m3);
            float s0 = 0.f, s1 = 0.f, s2 = 0.f, s3 = 0.f;
            for (int base = beg; base < end; base += 64) {
                int j = base + lane;
                if (j < end) {
                    int sid = csr[j];
                    float4 r0 = ((const float4*)p0)[sid];
                    s0 += __expf(lrelu(r0.x + r1.x) - m0);
                    s1 += __expf(lrelu(r0.y + r1.y) - m1);
                    s2 += __expf(lrelu(r0.z + r1.z) - m2);
                    s3 += __expf(lrelu(r0.w + r1.w) - m3);
                }
            }
            rsum4<64>(s0, s1, s2, s3);
            const float is0 = 1.f / (s0 + EPS_SM);
            const float is1 = 1.f / (s1 + EPS_SM);
            const float is2 = 1.f / (s2 + EPS_SM);
            const float is3 = 1.f / (s3 + EPS_SM);
            for (int base = beg; base < end; base += 64) {
                int cnt = min(64, end - base);
                int sid = 0;
                float w0 = 0.f, w1 = 0.f, w2 = 0.f, w3 = 0.f;
                if (lane < cnt) {
                    sid = csr[base + lane];
                    float4 r0 = ((const float4*)p0)[sid];
                    w0 = __expf(lrelu(r0.x + r1.x) - m0) * is0;
                    w1 = __expf(lrelu(r0.y + r1.y) - m1) * is1;
                    w2 = __expf(lrelu(r0.z + r1.z) - m2) * is2;
                    w3 = __expf(lrelu(r0.w + r1.w) - m3) * is3;
                }
                sdw[lane] = sid;
                wtw[lane] = make_uint2(pkh(w0, w1), pkh(w2, w3));
                const int npair = (cnt + 7) >> 3;
#pragma unroll 2
                for (int t = 0; t < npair; ++t) {
                    int pi = 4 * t + q;
                    uint2 sp = *(const uint2*)&sdw[2 * pi];
                    uint4 wp = *(const uint4*)&wtw[2 * pi];
                    uint4 u = *(const uint4*)(hpb + (((unsigned)sp.x << 8) + rowoff));
                    uint4 v = *(const uint4*)(hpb + (((unsigned)sp.y << 8) + rowoff));
                    unsigned wA = hlo ? wp.x : wp.y;
                    unsigned wB = hlo ? wp.z : wp.w;
                    unsigned wpk = __builtin_amdgcn_perm(wB, wA, wsel);
                    acc[0] = dot2(__builtin_amdgcn_perm(v.x, u.x, 0x05040100u), wpk, acc[0]);
                    acc[1] = dot2(__builtin_amdgcn_perm(v.x, u.x, 0x07060302u), wpk, acc[1]);
                    acc[2] = dot2(__builtin_amdgcn_perm(v.y, u.y, 0x05040100u), wpk, acc[2]);
                    acc[3] = dot2(__builtin_amdgcn_perm(v.y, u.y, 0x07060302u), wpk, acc[3]);
                    acc[4] = dot2(__builtin_amdgcn_perm(v.z, u.z, 0x05040100u), wpk, acc[4]);
                    acc[5] = dot2(__builtin_amdgcn_perm(v.z, u.z, 0x07060302u), wpk, acc[5]);
                    acc[6] = dot2(__builtin_amdgcn_perm(v.w, u.w, 0x05040100u), wpk, acc[6]);
                    acc[7] = dot2(__builtin_amdgcn_perm(v.w, u.w, 0x07060302u), wpk, acc[7]);
                }
            }
        }
    }

    // merge quarter-wave partials (each quarter covered a disjoint edge subset)
#pragma unroll
    for (int s = 16; s < 64; s <<= 1) {
#pragma unroll
        for (int k = 0; k < 8; ++k) acc[k] += __shfl_xor(acc[k], s, 64);
    }

    // combine + LayerNorm (lane holds channels 8*l15..8*l15+7; duplicated across quarters)
    size_t bb = (size_t)n * DIM;
    float4 hs0 = ((const float4*)(h_self + bb))[2 * l15];
    float4 hs1 = ((const float4*)(h_self + bb))[2 * l15 + 1];
    float4 b0 = ((const float4*)bias)[2 * l15];
    float4 b1 = ((const float4*)bias)[2 * l15 + 1];
    float x0 = hs0.x + acc[0] + b0.x;
    float x1 = hs0.y + acc[1] + b0.y;
    float x2 = hs0.z + acc[2] + b0.z;
    float x3 = hs0.w + acc[3] + b0.w;
    float y0 = hs1.x + acc[4] + b1.x;
    float y1 = hs1.y + acc[5] + b1.y;
    float y2 = hs1.z + acc[6] + b1.z;
    float y3 = hs1.w + acc[7] + b1.w;
    float sum = x0 + x1 + x2 + x3 + y0 + y1 + y2 + y3;
    float sq = x0 * x0 + x1 * x1 + x2 * x2 + x3 * x3
             + y0 * y0 + y1 * y1 + y2 * y2 + y3 * y3;
#pragma unroll
    for (int m = 1; m < 64; m <<= 1) {
        sum += __shfl_xor(sum, m, 64);
        sq += __shfl_xor(sq, m, 64);
    }
    float mean = sum * (1.f / 512.f);          // each channel counted 4x
    float var = sq * (1.f / 512.f) - mean * mean;
    float inv = rsqrtf(var + EPS_LN);
    if (lane < 16) {
        float4 g0 = ((const float4*)gamma)[2 * l15];
        float4 g1 = ((const float4*)gamma)[2 * l15 + 1];
        float4 be0 = ((const float4*)beta)[2 * l15];
        float4 be1 = ((const float4*)beta)[2 * l15 + 1];
        float4 o0 = make_float4((x0 - mean) * inv * g0.x + be0.x,
                                (x1 - mean) * inv * g0.y + be0.y,
                                (x2 - mean) * inv * g0.z + be0.z,
                                (x3 - mean) * inv * g0.w + be0.w);
        float4 o1 = make_float4((y0 - mean) * inv * g1.x + be1.x,
                                (y1 - mean) * inv * g1.y + be1.y,
                                (y2 - mean) * inv * g1.z + be1.z,
                                (y3 - mean) * inv * g1.w + be1.w);
        ((float4*)(out + bb))[2 * l15] = o0;
        ((float4*)(out + bb))[2 * l15 + 1] = o1;
    }
}

extern "C" void kernel_launch(void* const* d_in, const int* in_sizes, int n_in,
                              void* d_out, int out_size, void* d_ws, size_t ws_size,
                              hipStream_t stream) {
    const float* h      = (const float*)d_in[0];
    const int*   ei     = (const int*)d_in[1];
    const float* W      = (const float*)d_in[2];
    const float* W_self = (const float*)d_in[3];
    const float* a_in   = (const float*)d_in[4];
    const float* a_out  = (const float*)d_in[5];
    const float* bias   = (const float*)d_in[6];
    const float* gamma  = (const float*)d_in[7];
    const float* beta   = (const float*)d_in[8];
    float* out = (float*)d_out;

    const int N = in_sizes[0] / DIM;
    const int E = in_sizes[1] / 2;
    const int M = 2 * N;
    const int NBIN = (M + (1 << SH1) - 1) >> SH1;
    const int twoE = 2 * E;

    // workspace layout
    float* ws = (float*)d_ws;
    size_t off_f = 0;
    float* h_self = ws + off_f; off_f += (size_t)N * DIM;
    unsigned* hp_pk = (unsigned*)(ws + off_f); off_f += (size_t)N * 64;
    float* pA0 = ws + off_f; off_f += (size_t)N * 4;
    float* pA1 = ws + off_f; off_f += (size_t)N * 4;
    float* pB0 = ws + off_f; off_f += (size_t)N * 4;
    float* pB1 = ws + off_f; off_f += (size_t)N * 4;
    int* ip = (int*)(ws + off_f);
    size_t off_i = 0;
    int* cntmat = ip + off_i; off_i += (size_t)NBIN * PB;
    int* blkoff = ip + off_i; off_i += (size_t)NBIN * PB;
    int* btot   = ip + off_i; off_i += NBIN;
    int* bbase  = ip + off_i; off_i += (size_t)NBIN + 1;
    int* off    = ip + off_i; off_i += (size_t)M + 1;
    unsigned* rec = (unsigned*)(ip + off_i); off_i += (size_t)twoE;
    int* csr    = ip + off_i; off_i += (size_t)twoE;

    // ---- deterministic two-level CSR build ----
    part1a_k<<<PB, 256, 0, stream>>>(ei, cntmat, E, N, NBIN);
    scanB_k<<<NBIN, PB, 0, stream>>>(cntmat, blkoff, btot);
    scanC_k<<<1, 256, 0, stream>>>(btot, bbase, NBIN, twoE);
    part1b_k<<<PB, 256, 0, stream>>>(ei, bbase, blkoff, rec, E, N, NBIN);
    build2_k<<<NBIN, 256, 0, stream>>>(rec, bbase, off, csr, M, twoE, NBIN);

    // ---- fused projections + dots + pack ----
    dual_gemm_k<<<(N + GROWS - 1) / GROWS, 256, 0, stream>>>(h, W, W_self, a_in, a_out,
                                                             h_self, hp_pk, pA0, pA1, pB0, pB1, N);

    // ---- fused aggregate + LN ----
    node_aggr_ln_k<<<(N + 3) / 4, 256, 0, stream>>>(hp_pk, h_self, pA0, pA1, pB0, pB1,
                                                    off, csr, bias, gamma, beta, out, N);
}

// Round 2
// 417.093 us; speedup vs baseline: 1.0996x; 1.0898x over previous
//
#include <hip/hip_runtime.h>
#include <math.h>

#define HEADS 4
#define HD 32
#define DIM 128
#define NEG_SLOPE 0.2f
#define EPS_SM 1e-8f
#define EPS_LN 1e-5f
#define SH1 9              // 512 segments per coarse bin; NBIN = ceil(2N/512) <= 512
#define PB 128             // partition blocks
#define BCOLS 272          // 128 W + 128 W_self + 16 folded attention-dot cols

typedef _Float16 h2_t __attribute__((ext_vector_type(2)));
typedef _Float16 f16x8 __attribute__((ext_vector_type(8)));
typedef float f32x4 __attribute__((ext_vector_type(4)));

__device__ __forceinline__ float lrelu(float x) { return x > 0.f ? x : NEG_SLOPE * x; }
__device__ __forceinline__ unsigned pkh(float a, float b) {
    return __builtin_bit_cast(unsigned, __builtin_amdgcn_cvt_pkrtz(a, b));
}
__device__ __forceinline__ float dot2(unsigned a, unsigned b, float c) {
    return __builtin_amdgcn_fdot2(__builtin_bit_cast(h2_t, a), __builtin_bit_cast(h2_t, b), c, false);
}

template<int LIM> __device__ __forceinline__ void rmax4(float& a, float& b, float& c, float& d) {
#pragma unroll
    for (int s = 1; s < LIM; s <<= 1) {
        a = fmaxf(a, __shfl_xor(a, s, 64));
        b = fmaxf(b, __shfl_xor(b, s, 64));
        c = fmaxf(c, __shfl_xor(c, s, 64));
        d = fmaxf(d, __shfl_xor(d, s, 64));
    }
}
template<int LIM> __device__ __forceinline__ void rsum4(float& a, float& b, float& c, float& d) {
#pragma unroll
    for (int s = 1; s < LIM; s <<= 1) {
        a += __shfl_xor(a, s, 64);
        b += __shfl_xor(b, s, 64);
        c += __shfl_xor(c, s, 64);
        d += __shfl_xor(d, s, 64);
    }
}

// ---------------- B-matrix build: f16 transposed [BCOLS][128] ----------------
// rows 0..127   : W columns        (Bt[c][k] = W[k][c])
// rows 128..255 : W_self columns
// rows 256..271 : folded dot cols  (Bt[256+d*4+h][k] = sum_t W[k][32h+t]*avec[d][h][t])
//   d=0: a_in[:, :32], d=1: a_in[:, 32:], d=2: a_out[:, :32], d=3: a_out[:, 32:]
__global__ __launch_bounds__(128) void cvtb_k(const float* __restrict__ W,
                                              const float* __restrict__ V,
                                              const float* __restrict__ a_in,
                                              const float* __restrict__ a_out,
                                              _Float16* __restrict__ Bt) {
    const int c = blockIdx.x;
    const int k = threadIdx.x;
    float v;
    if (c < 128) {
        v = W[k * 128 + c];
    } else if (c < 256) {
        v = V[k * 128 + (c - 128)];
    } else {
        int d = (c - 256) >> 2, h = (c - 256) & 3;
        const float* a = (d < 2) ? a_in : a_out;
        int base = h * 64 + (d & 1) * 32;
        float s = 0.f;
#pragma unroll
        for (int t = 0; t < 32; ++t) s += W[k * 128 + 32 * h + t] * a[base + t];
        v = s;
    }
    Bt[c * 128 + k] = (_Float16)v;
}

// ---------------- MFMA GEMM: h(f32->f16) @ Bt^T, 64 rows/block ----------------
// wave w owns rows 16w..16w+15; 17 col-tiles of 16; K = 4 chunks of 32.
// A-frag: lane = row + 16*(k/8), 8 consecutive k (2x float4 load + cvt_pkrtz).
// B-frag: lane = col + 16*(k/8), 8 consecutive k (1x dwordx4 from f16 Bt).
// D-frag: col = lane&15, row = (lane>>4)*4 + reg   [m89-verified]
__global__ __launch_bounds__(256) void mfma_gemm_k(const float* __restrict__ h,
                                                   const _Float16* __restrict__ Bt,
                                                   float* __restrict__ h_self,
                                                   unsigned* __restrict__ hp_pk,
                                                   float* __restrict__ pA0, float* __restrict__ pA1,
                                                   float* __restrict__ pB0, float* __restrict__ pB1,
                                                   int N) {
    __shared__ _Float16 hs[64][128];   // 16 KB repack buffer for hp_pk
    const int tid = threadIdx.x;
    const int w = tid >> 6, l = tid & 63;
    const int l15 = l & 15;
    const int kg = l >> 4;             // 0..3
    const int row0 = blockIdx.x * 64;
    const int arow = row0 + 16 * w + l15;

    f32x4 acc[17];
#pragma unroll
    for (int j = 0; j < 17; ++j) {
        acc[j][0] = 0.f; acc[j][1] = 0.f; acc[j][2] = 0.f; acc[j][3] = 0.f;
    }

    const uint4* __restrict__ bt4 = (const uint4*)Bt;   // 16 uint4 per Bt row

#pragma unroll
    for (int kc = 0; kc < 4; ++kc) {
        union { unsigned u[4]; f16x8 v; } cv;
        if (arow < N) {
            float4 x0 = ((const float4*)h)[(size_t)arow * 32 + kc * 8 + kg * 2];
            float4 x1 = ((const float4*)h)[(size_t)arow * 32 + kc * 8 + kg * 2 + 1];
            cv.u[0] = pkh(x0.x, x0.y); cv.u[1] = pkh(x0.z, x0.w);
            cv.u[2] = pkh(x1.x, x1.y); cv.u[3] = pkh(x1.z, x1.w);
        } else {
            cv.u[0] = 0u; cv.u[1] = 0u; cv.u[2] = 0u; cv.u[3] = 0u;
        }
        f16x8 af = cv.v;
#pragma unroll
        for (int j = 0; j < 17; ++j) {
            int col = 16 * j + l15;
            union { uint4 q; f16x8 v; } bc;
            bc.q = bt4[col * 16 + kc * 4 + kg];
            acc[j] = __builtin_amdgcn_mfma_f32_16x16x32_f16(af, bc.v, acc[j], 0, 0, 0);
        }
    }

    // ---- epilogue ----
    const int r4 = kg * 4;             // D row offset within 16x16 tile
    const int c16 = l15, dsel = c16 >> 2, hh = c16 & 3;
    float* __restrict__ pd = (dsel == 0) ? pA0 : (dsel == 1) ? pA1 : (dsel == 2) ? pB0 : pB1;
#pragma unroll
    for (int r = 0; r < 4; ++r) {
        int grow = row0 + 16 * w + r4 + r;
        bool ok = grow < N;
        // h_self (cols 128..255)
#pragma unroll
        for (int j = 8; j < 16; ++j)
            if (ok) h_self[(size_t)grow * 128 + 16 * (j - 8) + l15] = acc[j][r];
        // folded attention dots (col-tile 16)
        if (ok) pd[grow * 4 + hh] = acc[16][r];
        // f16 projection rows -> LDS (cols 0..127)
#pragma unroll
        for (int j = 0; j < 8; ++j)
            hs[16 * w + r4 + r][16 * j + l15] = (_Float16)acc[j][r];
    }
    __syncthreads();
    const uint4* hsv = (const uint4*)&hs[0][0];    // 16 uint4 per row
#pragma unroll
    for (int p = 0; p < 4; ++p) {
        int chunk = tid + p * 256;                 // 0..1023 = 64 rows x 16 chunks
        int rrow = chunk >> 4, cg = chunk & 15;
        int grow = row0 + rrow;
        if (grow < N)
            ((uint4*)hp_pk)[(size_t)grow * 16 + cg] = hsv[rrow * 16 + cg];
    }
}

// ---------------- deterministic two-level CSR build (no global atomics) ----------------
__global__ __launch_bounds__(256) void part1a_k(const int* __restrict__ ei, int* __restrict__ cntmat,
                                                int E, int N, int NBIN) {
    __shared__ int lcnt[512];
    const int t = threadIdx.x;
    const int CH = (E + gridDim.x - 1) / gridDim.x;
    const int e0 = blockIdx.x * CH;
    const int e1 = min(e0 + CH, E);
    for (int i = t; i < 512; i += 256) lcnt[i] = 0;
    __syncthreads();
    for (int e = e0 + t; e < e1; e += 256) {
        int s = ei[e], d = ei[E + e];
        atomicAdd(&lcnt[d >> SH1], 1);
        atomicAdd(&lcnt[(N + s) >> SH1], 1);
    }
    __syncthreads();
    for (int i = t; i < NBIN; i += 256) cntmat[i * PB + blockIdx.x] = lcnt[i];
}

__global__ __launch_bounds__(128) void scanB_k(const int* __restrict__ cntmat,
                                               int* __restrict__ blkoff, int* __restrict__ btot) {
    __shared__ int ls[PB];
    const int bin = blockIdx.x;
    const int t = threadIdx.x;
    int v = cntmat[bin * PB + t];
    ls[t] = v;
    __syncthreads();
#pragma unroll
    for (int d = 1; d < PB; d <<= 1) {
        int u = (t >= d) ? ls[t - d] : 0;
        __syncthreads();
        ls[t] += u;
        __syncthreads();
    }
    blkoff[bin * PB + t] = ls[t] - v;
    if (t == PB - 1) btot[bin] = ls[t];
}

__global__ __launch_bounds__(256) void scanC_k(const int* __restrict__ btot,
                                               int* __restrict__ bbase, int NBIN, int twoE) {
    __shared__ int ls[256];
    int t = threadIdx.x;
    int i0 = 2 * t, i1 = 2 * t + 1;
    int v0 = (i0 < NBIN) ? btot[i0] : 0;
    int v1 = (i1 < NBIN) ? btot[i1] : 0;
    int pair = v0 + v1;
    ls[t] = pair;
    __syncthreads();
#pragma unroll
    for (int d = 1; d < 256; d <<= 1) {
        int u = (t >= d) ? ls[t - d] : 0;
        __syncthreads();
        ls[t] += u;
        __syncthreads();
    }
    int excl = ls[t] - pair;
    if (i0 < NBIN) bbase[i0] = excl;
    if (i1 < NBIN) bbase[i1] = excl + v0;
    if (t == 0) bbase[NBIN] = twoE;
}

__global__ __launch_bounds__(256) void part1b_k(const int* __restrict__ ei,
                                                const int* __restrict__ bbase,
                                                const int* __restrict__ blkoff,
                                                unsigned* __restrict__ rec, int E, int N, int NBIN) {
    __shared__ int gb[512];
    __shared__ int lcur[512];
    const int t = threadIdx.x;
    const int CH = (E + gridDim.x - 1) / gridDim.x;
    const int e0 = blockIdx.x * CH;
    const int e1 = min(e0 + CH, E);
    for (int i = t; i < 512; i += 256) lcur[i] = 0;
    for (int i = t; i < NBIN; i += 256) gb[i] = bbase[i] + blkoff[i * PB + blockIdx.x];
    __syncthreads();
    for (int e = e0 + t; e < e1; e += 256) {
        int s = ei[e], d = ei[E + e];
        int b1 = d >> SH1;
        int r1 = atomicAdd(&lcur[b1], 1);
        rec[gb[b1] + r1] = (unsigned)s | ((unsigned)(d & 511) << 20);
        int so = N + s;
        int b2 = so >> SH1;
        int r2 = atomicAdd(&lcur[b2], 1);
        rec[gb[b2] + r2] = (unsigned)d | ((unsigned)(so & 511) << 20);
    }
}

__global__ __launch_bounds__(256) void build2_k(const unsigned* __restrict__ rec,
                                                const int* __restrict__ bbase,
                                                int* __restrict__ off, int* __restrict__ csr,
                                                int M, int twoE, int NBIN) {
    __shared__ int lcnt[512];
    __shared__ int lcur[512];
    __shared__ int ls[256];
    const int b = blockIdx.x;
    const int t = threadIdx.x;
    const int base = bbase[b];
    const int cnt = bbase[b + 1] - base;
    const int seg0 = b << SH1;
    for (int i = t; i < 512; i += 256) lcnt[i] = 0;
    __syncthreads();
    for (int k = t; k < cnt; k += 256) atomicAdd(&lcnt[rec[base + k] >> 20], 1);
    __syncthreads();
    int v0 = lcnt[2 * t], v1 = lcnt[2 * t + 1];
    int pair = v0 + v1;
    ls[t] = pair;
    __syncthreads();
#pragma unroll
    for (int d = 1; d < 256; d <<= 1) {
        int u = (t >= d) ? ls[t - d] : 0;
        __syncthreads();
        ls[t] += u;
        __syncthreads();
    }
    int excl = ls[t] - pair;
    lcur[2 * t] = excl;
    lcur[2 * t + 1] = excl + v0;
    int sg = seg0 + 2 * t;
    if (sg < M) off[sg] = base + excl;
    if (sg + 1 < M) off[sg + 1] = base + excl + v0;
    if (b == NBIN - 1 && t == 0) off[M] = twoE;
    __syncthreads();
    for (int k = t; k < cnt; k += 256) {
        unsigned r = rec[base + k];
        int pos = atomicAdd(&lcur[r >> 20], 1);
        csr[base + pos] = (int)(r & 0xFFFFFu);
    }
}

// ---------------- fused: per-node softmax-aggregate + combine + LN ----------------
// hp rows are plain f16[128]. Quarter-wave handles 2 edges/iter: per packed word
// (2c,2c+1) of rows A,B, v_perm builds (A_c,B_c) and v_dot2_f32_f16 does both MACs.
__global__ __launch_bounds__(256) void node_aggr_ln_k(const unsigned* __restrict__ hp_pk,
                                                      const float* __restrict__ h_self,
                                                      const float* __restrict__ pA0, const float* __restrict__ pA1,
                                                      const float* __restrict__ pB0, const float* __restrict__ pB1,
                                                      const int* __restrict__ off, const int* __restrict__ csr,
                                                      const float* __restrict__ bias,
                                                      const float* __restrict__ gamma,
                                                      const float* __restrict__ beta,
                                                      float* __restrict__ out, int N) {
    __shared__ int sds[4][64];     // per-edge sender id
    __shared__ uint2 wts[4][64];   // per-edge f16 head weights: {pk(w0,w1), pk(w2,w3)}
    const int wave = threadIdx.x >> 6;
    const int lane = threadIdx.x & 63;
    const int n = blockIdx.x * 4 + wave;
    if (n >= N) return;
    const int l15 = lane & 15;
    const int q = lane >> 4;
    // lane covers channels 8*l15..8*l15+7, all in head l15>>2
    const unsigned wsel = (l15 & 4) ? 0x07060302u : 0x05040100u;  // pick f16 (h&1) of weight words
    const bool hlo = (l15 < 8);                                   // head < 2
    int* sdw = sds[wave];
    uint2* wtw = wts[wave];
    const char* hpb = (const char*)hp_pk;   // row stride 256 B
    const unsigned rowoff = (unsigned)l15 << 4;

    float acc[8];
#pragma unroll
    for (int k = 0; k < 8; ++k) acc[k] = 0.f;

#pragma unroll
    for (int dir = 0; dir < 2; ++dir) {
        const int seg = (dir == 0) ? n : N + n;
        const int beg = off[seg], end = off[seg + 1];
        const int len = end - beg;
        if (len == 0) continue;
        const float* __restrict__ p0 = (dir == 0) ? pA0 : pB0;
        const float* __restrict__ p1 = (dir == 0) ? pA1 : pB1;
        float4 r1 = ((const float4*)p1)[n];

        if (len <= 64) {
            int sid = 0;
            float e0 = -INFINITY, e1 = -INFINITY, e2 = -INFINITY, e3 = -INFINITY;
            if (lane < len) {
                sid = csr[beg + lane];
                float4 r0 = ((const float4*)p0)[sid];
                e0 = lrelu(r0.x + r1.x);
                e1 = lrelu(r0.y + r1.y);
                e2 = lrelu(r0.z + r1.z);
                e3 = lrelu(r0.w + r1.w);
            }
            float m0 = e0, m1 = e1, m2 = e2, m3 = e3;
            if (len <= 16)      rmax4<16>(m0, m1, m2, m3);
            else if (len <= 32) rmax4<32>(m0, m1, m2, m3);
            else                rmax4<64>(m0, m1, m2, m3);
            float w0 = 0.f, w1 = 0.f, w2 = 0.f, w3 = 0.f;
            if (lane < len) {
                w0 = __expf(e0 - m0); w1 = __expf(e1 - m1);
                w2 = __expf(e2 - m2); w3 = __expf(e3 - m3);
            }
            float s0 = w0, s1 = w1, s2 = w2, s3 = w3;
            if (len <= 16)      rsum4<16>(s0, s1, s2, s3);
            else if (len <= 32) rsum4<32>(s0, s1, s2, s3);
            else                rsum4<64>(s0, s1, s2, s3);
            w0 *= 1.f / (s0 + EPS_SM);
            w1 *= 1.f / (s1 + EPS_SM);
            w2 *= 1.f / (s2 + EPS_SM);
            w3 *= 1.f / (s3 + EPS_SM);
            sdw[lane] = sid;
            wtw[lane] = make_uint2(pkh(w0, w1), pkh(w2, w3));
            const int npair = (len + 7) >> 3;   // 8 edges (4 pairs) per iter
#pragma unroll 2
            for (int t = 0; t < npair; ++t) {
                int pi = 4 * t + q;
                uint2 sp = *(const uint2*)&sdw[2 * pi];
                uint4 wp = *(const uint4*)&wtw[2 * pi];
                uint4 u = *(const uint4*)(hpb + (((unsigned)sp.x << 8) + rowoff));
                uint4 v = *(const uint4*)(hpb + (((unsigned)sp.y << 8) + rowoff));
                unsigned wA = hlo ? wp.x : wp.y;
                unsigned wB = hlo ? wp.z : wp.w;
                unsigned wpk = __builtin_amdgcn_perm(wB, wA, wsel);
                acc[0] = dot2(__builtin_amdgcn_perm(v.x, u.x, 0x05040100u), wpk, acc[0]);
                acc[1] = dot2(__builtin_amdgcn_perm(v.x, u.x, 0x07060302u), wpk, acc[1]);
                acc[2] = dot2(__builtin_amdgcn_perm(v.y, u.y, 0x05040100u), wpk, acc[2]);
                acc[3] = dot2(__builtin_amdgcn_perm(v.y, u.y, 0x07060302u), wpk, acc[3]);
                acc[4] = dot2(__builtin_amdgcn_perm(v.z, u.z, 0x05040100u), wpk, acc[4]);
                acc[5] = dot2(__builtin_amdgcn_perm(v.z, u.z, 0x07060302u), wpk, acc[5]);
                acc[6] = dot2(__builtin_amdgcn_perm(v.w, u.w, 0x05040100u), wpk, acc[6]);
                acc[7] = dot2(__builtin_amdgcn_perm(v.w, u.w, 0x07060302u), wpk, acc[7]);
            }
        } else {
            // rare: deg > 64 — 2 reduction passes, then chunked
            float m0 = -INFINITY, m1 = -INFINITY, m2 = -INFINITY, m3 = -INFINITY;
            for (int base = beg; base < end; base += 64) {
                int j = base + lane;
                if (j < end) {
                    int sid = csr[j];
                    float4 r0 = ((const float4*)p0)[sid];
                    m0 = fmaxf(m0, lrelu(r0.x + r1.x));
                    m1 = fmaxf(m1, lrelu(r0.y + r1.y));
                    m2 = fmaxf(m2, lrelu(r0.z + r1.z));
                    m3 = fmaxf(m3, lrelu(r0.w + r1.w));
                }
            }
            rmax4<64>(m0, m1, m2, m3);
            float s0 = 0.f, s1 = 0.f, s2 = 0.f, s3 = 0.f;
            for (int base = beg; base < end; base += 64) {
                int j = base + lane;
                if (j < end) {
                    int sid = csr[j];
                    float4 r0 = ((const float4*)p0)[sid];
                    s0 += __expf(lrelu(r0.x + r1.x) - m0);
                    s1 += __expf(lrelu(r0.y + r1.y) - m1);
                    s2 += __expf(lrelu(r0.z + r1.z) - m2);
                    s3 += __expf(lrelu(r0.w + r1.w) - m3);
                }
            }
            rsum4<64>(s0, s1, s2, s3);
            const float is0 = 1.f / (s0 + EPS_SM);
            const float is1 = 1.f / (s1 + EPS_SM);
            const float is2 = 1.f / (s2 + EPS_SM);
            const float is3 = 1.f / (s3 + EPS_SM);
            for (int base = beg; base < end; base += 64) {
                int cnt = min(64, end - base);
                int sid = 0;
                float w0 = 0.f, w1 = 0.f, w2 = 0.f, w3 = 0.f;
                if (lane < cnt) {
                    sid = csr[base + lane];
                    float4 r0 = ((const float4*)p0)[sid];
                    w0 = __expf(lrelu(r0.x + r1.x) - m0) * is0;
                    w1 = __expf(lrelu(r0.y + r1.y) - m1) * is1;
                    w2 = __expf(lrelu(r0.z + r1.z) - m2) * is2;
                    w3 = __expf(lrelu(r0.w + r1.w) - m3) * is3;
                }
                sdw[lane] = sid;
                wtw[lane] = make_uint2(pkh(w0, w1), pkh(w2, w3));
                const int npair = (cnt + 7) >> 3;
#pragma unroll 2
                for (int t = 0; t < npair; ++t) {
                    int pi = 4 * t + q;
                    uint2 sp = *(const uint2*)&sdw[2 * pi];
                    uint4 wp = *(const uint4*)&wtw[2 * pi];
                    uint4 u = *(const uint4*)(hpb + (((unsigned)sp.x << 8) + rowoff));
                    uint4 v = *(const uint4*)(hpb + (((unsigned)sp.y << 8) + rowoff));
                    unsigned wA = hlo ? wp.x : wp.y;
                    unsigned wB = hlo ? wp.z : wp.w;
                    unsigned wpk = __builtin_amdgcn_perm(wB, wA, wsel);
                    acc[0] = dot2(__builtin_amdgcn_perm(v.x, u.x, 0x05040100u), wpk, acc[0]);
                    acc[1] = dot2(__builtin_amdgcn_perm(v.x, u.x, 0x07060302u), wpk, acc[1]);
                    acc[2] = dot2(__builtin_amdgcn_perm(v.y, u.y, 0x05040100u), wpk, acc[2]);
                    acc[3] = dot2(__builtin_amdgcn_perm(v.y, u.y, 0x07060302u), wpk, acc[3]);
                    acc[4] = dot2(__builtin_amdgcn_perm(v.z, u.z, 0x05040100u), wpk, acc[4]);
                    acc[5] = dot2(__builtin_amdgcn_perm(v.z, u.z, 0x07060302u), wpk, acc[5]);
                    acc[6] = dot2(__builtin_amdgcn_perm(v.w, u.w, 0x05040100u), wpk, acc[6]);
                    acc[7] = dot2(__builtin_amdgcn_perm(v.w, u.w, 0x07060302u), wpk, acc[7]);
                }
            }
        }
    }

    // merge quarter-wave partials (each quarter covered a disjoint edge subset)
#pragma unroll
    for (int s = 16; s < 64; s <<= 1) {
#pragma unroll
        for (int k = 0; k < 8; ++k) acc[k] += __shfl_xor(acc[k], s, 64);
    }

    // combine + LayerNorm (lane holds channels 8*l15..8*l15+7; duplicated across quarters)
    size_t bb = (size_t)n * DIM;
    float4 hs0 = ((const float4*)(h_self + bb))[2 * l15];
    float4 hs1 = ((const float4*)(h_self + bb))[2 * l15 + 1];
    float4 b0 = ((const float4*)bias)[2 * l15];
    float4 b1 = ((const float4*)bias)[2 * l15 + 1];
    float x0 = hs0.x + acc[0] + b0.x;
    float x1 = hs0.y + acc[1] + b0.y;
    float x2 = hs0.z + acc[2] + b0.z;
    float x3 = hs0.w + acc[3] + b0.w;
    float y0 = hs1.x + acc[4] + b1.x;
    float y1 = hs1.y + acc[5] + b1.y;
    float y2 = hs1.z + acc[6] + b1.z;
    float y3 = hs1.w + acc[7] + b1.w;
    float sum = x0 + x1 + x2 + x3 + y0 + y1 + y2 + y3;
    float sq = x0 * x0 + x1 * x1 + x2 * x2 + x3 * x3
             + y0 * y0 + y1 * y1 + y2 * y2 + y3 * y3;
#pragma unroll
    for (int m = 1; m < 64; m <<= 1) {
        sum += __shfl_xor(sum, m, 64);
        sq += __shfl_xor(sq, m, 64);
    }
    float mean = sum * (1.f / 512.f);          // each channel counted 4x
    float var = sq * (1.f / 512.f) - mean * mean;
    float inv = rsqrtf(var + EPS_LN);
    if (lane < 16) {
        float4 g0 = ((const float4*)gamma)[2 * l15];
        float4 g1 = ((const float4*)gamma)[2 * l15 + 1];
        float4 be0 = ((const float4*)beta)[2 * l15];
        float4 be1 = ((const float4*)beta)[2 * l15 + 1];
        float4 o0 = make_float4((x0 - mean) * inv * g0.x + be0.x,
                                (x1 - mean) * inv * g0.y + be0.y,
                                (x2 - mean) * inv * g0.z + be0.z,
                                (x3 - mean) * inv * g0.w + be0.w);
        float4 o1 = make_float4((y0 - mean) * inv * g1.x + be1.x,
                                (y1 - mean) * inv * g1.y + be1.y,
                                (y2 - mean) * inv * g1.z + be1.z,
                                (y3 - mean) * inv * g1.w + be1.w);
        ((float4*)(out + bb))[2 * l15] = o0;
        ((float4*)(out + bb))[2 * l15 + 1] = o1;
    }
}

extern "C" void kernel_launch(void* const* d_in, const int* in_sizes, int n_in,
                              void* d_out, int out_size, void* d_ws, size_t ws_size,
                              hipStream_t stream) {
    const float* h      = (const float*)d_in[0];
    const int*   ei     = (const int*)d_in[1];
    const float* W      = (const float*)d_in[2];
    const float* W_self = (const float*)d_in[3];
    const float* a_in   = (const float*)d_in[4];
    const float* a_out  = (const float*)d_in[5];
    const float* bias   = (const float*)d_in[6];
    const float* gamma  = (const float*)d_in[7];
    const float* beta   = (const float*)d_in[8];
    float* out = (float*)d_out;

    const int N = in_sizes[0] / DIM;
    const int E = in_sizes[1] / 2;
    const int M = 2 * N;
    const int NBIN = (M + (1 << SH1) - 1) >> SH1;
    const int twoE = 2 * E;

    // workspace layout
    float* ws = (float*)d_ws;
    size_t off_f = 0;
    float* h_self = ws + off_f; off_f += (size_t)N * DIM;
    unsigned* hp_pk = (unsigned*)(ws + off_f); off_f += (size_t)N * 64;
    float* pA0 = ws + off_f; off_f += (size_t)N * 4;
    float* pA1 = ws + off_f; off_f += (size_t)N * 4;
    float* pB0 = ws + off_f; off_f += (size_t)N * 4;
    float* pB1 = ws + off_f; off_f += (size_t)N * 4;
    int* ip = (int*)(ws + off_f);
    size_t off_i = 0;
    int* cntmat = ip + off_i; off_i += (size_t)NBIN * PB;
    int* blkoff = ip + off_i; off_i += (size_t)NBIN * PB;
    int* btot   = ip + off_i; off_i += NBIN;
    int* bbase  = ip + off_i; off_i += (size_t)NBIN + 1;
    int* off    = ip + off_i; off_i += (size_t)M + 1;
    unsigned* rec = (unsigned*)(ip + off_i); off_i += (size_t)twoE;
    int* csr    = ip + off_i; off_i += (size_t)twoE;
    _Float16* Bt = (_Float16*)(ip + off_i); off_i += (size_t)(BCOLS * 128) / 2;

    // ---- B-matrix build (f16 transpose + folded dot columns) ----
    cvtb_k<<<BCOLS, 128, 0, stream>>>(W, W_self, a_in, a_out, Bt);

    // ---- deterministic two-level CSR build ----
    part1a_k<<<PB, 256, 0, stream>>>(ei, cntmat, E, N, NBIN);
    scanB_k<<<NBIN, PB, 0, stream>>>(cntmat, blkoff, btot);
    scanC_k<<<1, 256, 0, stream>>>(btot, bbase, NBIN, twoE);
    part1b_k<<<PB, 256, 0, stream>>>(ei, bbase, blkoff, rec, E, N, NBIN);
    build2_k<<<NBIN, 256, 0, stream>>>(rec, bbase, off, csr, M, twoE, NBIN);

    // ---- MFMA projections + folded dots + f16 pack ----
    mfma_gemm_k<<<(N + 63) / 64, 256, 0, stream>>>(h, Bt, h_self, hp_pk,
                                                   pA0, pA1, pB0, pB1, N);

    // ---- fused aggregate + LN ----
    node_aggr_ln_k<<<(N + 3) / 4, 256, 0, stream>>>(hp_pk, h_self, pA0, pA1, pB0, pB1,
                                                    off, csr, bias, gamma, beta, out, N);
}

// Round 3
// 398.139 us; speedup vs baseline: 1.1520x; 1.0476x over previous
//
#include <hip/hip_runtime.h>
#include <math.h>

#define HEADS 4
#define HD 32
#define DIM 128
#define NEG_SLOPE 0.2f
#define EPS_SM 1e-8f
#define EPS_LN 1e-5f
#define SH1 9              // 512 segments per coarse bin; NBIN = ceil(2N/512) <= 512
#define PB 128             // partition blocks
#define BCOLS 272          // 128 W + 128 W_self + 16 folded attention-dot cols

typedef _Float16 h2_t __attribute__((ext_vector_type(2)));
typedef _Float16 f16x8 __attribute__((ext_vector_type(8)));
typedef float f32x4 __attribute__((ext_vector_type(4)));

__device__ __forceinline__ float lrelu(float x) { return x > 0.f ? x : NEG_SLOPE * x; }
__device__ __forceinline__ unsigned pkh(float a, float b) {
    return __builtin_bit_cast(unsigned, __builtin_amdgcn_cvt_pkrtz(a, b));
}
__device__ __forceinline__ float dot2(unsigned a, unsigned b, float c) {
    return __builtin_amdgcn_fdot2(__builtin_bit_cast(h2_t, a), __builtin_bit_cast(h2_t, b), c, false);
}
__device__ __forceinline__ float lo16(unsigned u) { return (float)__builtin_bit_cast(h2_t, u)[0]; }
__device__ __forceinline__ float hi16(unsigned u) { return (float)__builtin_bit_cast(h2_t, u)[1]; }

template<int LIM> __device__ __forceinline__ void rmax4(float& a, float& b, float& c, float& d) {
#pragma unroll
    for (int s = 1; s < LIM; s <<= 1) {
        a = fmaxf(a, __shfl_xor(a, s, 64));
        b = fmaxf(b, __shfl_xor(b, s, 64));
        c = fmaxf(c, __shfl_xor(c, s, 64));
        d = fmaxf(d, __shfl_xor(d, s, 64));
    }
}
template<int LIM> __device__ __forceinline__ void rsum4(float& a, float& b, float& c, float& d) {
#pragma unroll
    for (int s = 1; s < LIM; s <<= 1) {
        a += __shfl_xor(a, s, 64);
        b += __shfl_xor(b, s, 64);
        c += __shfl_xor(c, s, 64);
        d += __shfl_xor(d, s, 64);
    }
}

// shared aggregation inner loop: 8 edges (4 pairs across quarter-waves) per iter
__device__ __forceinline__ void aggr_pairs(int cnt, const int* __restrict__ sdw,
                                           const uint2* __restrict__ wtw,
                                           const char* __restrict__ hpb,
                                           unsigned rowoff, int q, bool hlo, unsigned wsel,
                                           float (&acc)[8]) {
    const int npair = (cnt + 7) >> 3;
#pragma unroll 2
    for (int t = 0; t < npair; ++t) {
        int pi = 4 * t + q;
        uint2 sp = *(const uint2*)&sdw[2 * pi];
        uint4 wp = *(const uint4*)&wtw[2 * pi];
        uint4 u = *(const uint4*)(hpb + (((unsigned)sp.x << 8) + rowoff));
        uint4 v = *(const uint4*)(hpb + (((unsigned)sp.y << 8) + rowoff));
        unsigned wA = hlo ? wp.x : wp.y;
        unsigned wB = hlo ? wp.z : wp.w;
        unsigned wpk = __builtin_amdgcn_perm(wB, wA, wsel);
        acc[0] = dot2(__builtin_amdgcn_perm(v.x, u.x, 0x05040100u), wpk, acc[0]);
        acc[1] = dot2(__builtin_amdgcn_perm(v.x, u.x, 0x07060302u), wpk, acc[1]);
        acc[2] = dot2(__builtin_amdgcn_perm(v.y, u.y, 0x05040100u), wpk, acc[2]);
        acc[3] = dot2(__builtin_amdgcn_perm(v.y, u.y, 0x07060302u), wpk, acc[3]);
        acc[4] = dot2(__builtin_amdgcn_perm(v.z, u.z, 0x05040100u), wpk, acc[4]);
        acc[5] = dot2(__builtin_amdgcn_perm(v.z, u.z, 0x07060302u), wpk, acc[5]);
        acc[6] = dot2(__builtin_amdgcn_perm(v.w, u.w, 0x05040100u), wpk, acc[6]);
        acc[7] = dot2(__builtin_amdgcn_perm(v.w, u.w, 0x07060302u), wpk, acc[7]);
    }
}

// ---------------- part1a (bin histogram) + folded cvtb (Bt build) ----------------
// blocks [0,PB): per-block bin histogram -> cntmat[bin*PB + blk]
// blocks [PB, PB+BCOLS/2): build f16 Bt[BCOLS][128]
//   rows 0..127: W cols; 128..255: W_self cols; 256..271: folded dot cols
__global__ __launch_bounds__(256) void part1a_k(const int* __restrict__ ei, int* __restrict__ cntmat,
                                                int E, int N, int NBIN,
                                                const float* __restrict__ W,
                                                const float* __restrict__ V,
                                                const float* __restrict__ a_in,
                                                const float* __restrict__ a_out,
                                                _Float16* __restrict__ Bt) {
    __shared__ int lcnt[512];
    const int t = threadIdx.x;
    if (blockIdx.x >= PB) {
        int c = (blockIdx.x - PB) * 2 + (t >> 7);   // 0..BCOLS-1
        int k = t & 127;
        float v;
        if (c < 128) {
            v = W[k * 128 + c];
        } else if (c < 256) {
            v = V[k * 128 + (c - 128)];
        } else {
            int d = (c - 256) >> 2, hh = (c - 256) & 3;
            const float* a = (d < 2) ? a_in : a_out;
            int base = hh * 64 + (d & 1) * 32;
            float s = 0.f;
#pragma unroll
            for (int tt = 0; tt < 32; ++tt) s += W[k * 128 + 32 * hh + tt] * a[base + tt];
            v = s;
        }
        Bt[c * 128 + k] = (_Float16)v;
        return;
    }
    const int CH = (E + PB - 1) / PB;
    const int e0 = blockIdx.x * CH;
    const int e1 = min(e0 + CH, E);
    for (int i = t; i < 512; i += 256) lcnt[i] = 0;
    __syncthreads();
    for (int e = e0 + t; e < e1; e += 256) {
        int s = ei[e], d = ei[E + e];
        atomicAdd(&lcnt[d >> SH1], 1);
        atomicAdd(&lcnt[(N + s) >> SH1], 1);
    }
    __syncthreads();
    for (int i = t; i < NBIN; i += 256) cntmat[i * PB + blockIdx.x] = lcnt[i];
}

// ---------------- MFMA GEMM: h(f32->f16) @ Bt^T, 64 rows/block ----------------
// wave w owns rows 16w..16w+15; 17 col-tiles of 16; K = 4 chunks of 32.
// D-frag: col = lane&15, row = (lane>>4)*4 + reg   [m89-verified]
// Outputs: hp_pk (f16 W-proj rows), hs_pk (f16 self-proj rows), folded dots.
__global__ __launch_bounds__(256) void mfma_gemm_k(const float* __restrict__ h,
                                                   const _Float16* __restrict__ Bt,
                                                   unsigned* __restrict__ hs_pk,
                                                   unsigned* __restrict__ hp_pk,
                                                   float* __restrict__ pA0, float* __restrict__ pA1,
                                                   float* __restrict__ pB0, float* __restrict__ pB1,
                                                   int N) {
    __shared__ _Float16 hs[64][128];    // W-proj repack
    __shared__ _Float16 hss[64][128];   // self-proj repack
    const int tid = threadIdx.x;
    const int w = tid >> 6, l = tid & 63;
    const int l15 = l & 15;
    const int kg = l >> 4;             // 0..3
    const int row0 = blockIdx.x * 64;
    const int arow = row0 + 16 * w + l15;

    f32x4 acc[17];
#pragma unroll
    for (int j = 0; j < 17; ++j) {
        acc[j][0] = 0.f; acc[j][1] = 0.f; acc[j][2] = 0.f; acc[j][3] = 0.f;
    }

    const uint4* __restrict__ bt4 = (const uint4*)Bt;   // 16 uint4 per Bt row

#pragma unroll
    for (int kc = 0; kc < 4; ++kc) {
        union { unsigned u[4]; f16x8 v; } cv;
        if (arow < N) {
            float4 x0 = ((const float4*)h)[(size_t)arow * 32 + kc * 8 + kg * 2];
            float4 x1 = ((const float4*)h)[(size_t)arow * 32 + kc * 8 + kg * 2 + 1];
            cv.u[0] = pkh(x0.x, x0.y); cv.u[1] = pkh(x0.z, x0.w);
            cv.u[2] = pkh(x1.x, x1.y); cv.u[3] = pkh(x1.z, x1.w);
        } else {
            cv.u[0] = 0u; cv.u[1] = 0u; cv.u[2] = 0u; cv.u[3] = 0u;
        }
        f16x8 af = cv.v;
#pragma unroll
        for (int j = 0; j < 17; ++j) {
            int col = 16 * j + l15;
            union { uint4 q; f16x8 v; } bc;
            bc.q = bt4[col * 16 + kc * 4 + kg];
            acc[j] = __builtin_amdgcn_mfma_f32_16x16x32_f16(af, bc.v, acc[j], 0, 0, 0);
        }
    }

    // ---- epilogue: everything goes through LDS f16 repack ----
    const int r4 = kg * 4;             // D row offset within 16x16 tile
    const int dsel = l15 >> 2, hh = l15 & 3;
    float* __restrict__ pd = (dsel == 0) ? pA0 : (dsel == 1) ? pA1 : (dsel == 2) ? pB0 : pB1;
#pragma unroll
    for (int r = 0; r < 4; ++r) {
        int lr = 16 * w + r4 + r;
        int grow = row0 + lr;
#pragma unroll
        for (int j = 0; j < 8; ++j)
            hs[lr][16 * j + l15] = (_Float16)acc[j][r];
#pragma unroll
        for (int j = 8; j < 16; ++j)
            hss[lr][16 * (j - 8) + l15] = (_Float16)acc[j][r];
        if (grow < N) pd[grow * 4 + hh] = acc[16][r];
    }
    __syncthreads();
    const uint4* hsv = (const uint4*)&hs[0][0];     // 16 uint4 per row
    const uint4* hssv = (const uint4*)&hss[0][0];
#pragma unroll
    for (int p = 0; p < 4; ++p) {
        int chunk = tid + p * 256;                  // 0..1023 = 64 rows x 16 chunks
        int rrow = chunk >> 4, cg = chunk & 15;
        int grow = row0 + rrow;
        if (grow < N) {
            ((uint4*)hp_pk)[(size_t)grow * 16 + cg] = hsv[rrow * 16 + cg];
            ((uint4*)hs_pk)[(size_t)grow * 16 + cg] = hssv[rrow * 16 + cg];
        }
    }
}

// ---------------- deterministic two-level CSR build (no global atomics) ----------------
__global__ __launch_bounds__(128) void scanB_k(const int* __restrict__ cntmat,
                                               int* __restrict__ blkoff, int* __restrict__ btot) {
    __shared__ int ls[PB];
    const int bin = blockIdx.x;
    const int t = threadIdx.x;
    int v = cntmat[bin * PB + t];
    ls[t] = v;
    __syncthreads();
#pragma unroll
    for (int d = 1; d < PB; d <<= 1) {
        int u = (t >= d) ? ls[t - d] : 0;
        __syncthreads();
        ls[t] += u;
        __syncthreads();
    }
    blkoff[bin * PB + t] = ls[t] - v;
    if (t == PB - 1) btot[bin] = ls[t];
}

__global__ __launch_bounds__(256) void scanC_k(const int* __restrict__ btot,
                                               int* __restrict__ bbase, int NBIN, int twoE) {
    __shared__ int ls[256];
    int t = threadIdx.x;
    int i0 = 2 * t, i1 = 2 * t + 1;
    int v0 = (i0 < NBIN) ? btot[i0] : 0;
    int v1 = (i1 < NBIN) ? btot[i1] : 0;
    int pair = v0 + v1;
    ls[t] = pair;
    __syncthreads();
#pragma unroll
    for (int d = 1; d < 256; d <<= 1) {
        int u = (t >= d) ? ls[t - d] : 0;
        __syncthreads();
        ls[t] += u;
        __syncthreads();
    }
    int excl = ls[t] - pair;
    if (i0 < NBIN) bbase[i0] = excl;
    if (i1 < NBIN) bbase[i1] = excl + v0;
    if (t == 0) bbase[NBIN] = twoE;
}

__global__ __launch_bounds__(256) void part1b_k(const int* __restrict__ ei,
                                                const int* __restrict__ bbase,
                                                const int* __restrict__ blkoff,
                                                unsigned* __restrict__ rec, int E, int N, int NBIN) {
    __shared__ int gb[512];
    __shared__ int lcur[512];
    const int t = threadIdx.x;
    const int CH = (E + gridDim.x - 1) / gridDim.x;
    const int e0 = blockIdx.x * CH;
    const int e1 = min(e0 + CH, E);
    for (int i = t; i < 512; i += 256) lcur[i] = 0;
    for (int i = t; i < NBIN; i += 256) gb[i] = bbase[i] + blkoff[i * PB + blockIdx.x];
    __syncthreads();
    for (int e = e0 + t; e < e1; e += 256) {
        int s = ei[e], d = ei[E + e];
        int b1 = d >> SH1;
        int r1 = atomicAdd(&lcur[b1], 1);
        rec[gb[b1] + r1] = (unsigned)s | ((unsigned)(d & 511) << 20);
        int so = N + s;
        int b2 = so >> SH1;
        int r2 = atomicAdd(&lcur[b2], 1);
        rec[gb[b2] + r2] = (unsigned)d | ((unsigned)(so & 511) << 20);
    }
}

__global__ __launch_bounds__(256) void build2_k(const unsigned* __restrict__ rec,
                                                const int* __restrict__ bbase,
                                                int* __restrict__ off, int* __restrict__ csr,
                                                int M, int twoE, int NBIN) {
    __shared__ int lcnt[512];
    __shared__ int lcur[512];
    __shared__ int ls[256];
    const int b = blockIdx.x;
    const int t = threadIdx.x;
    const int base = bbase[b];
    const int cnt = bbase[b + 1] - base;
    const int seg0 = b << SH1;
    for (int i = t; i < 512; i += 256) lcnt[i] = 0;
    __syncthreads();
    for (int k = t; k < cnt; k += 256) atomicAdd(&lcnt[rec[base + k] >> 20], 1);
    __syncthreads();
    int v0 = lcnt[2 * t], v1 = lcnt[2 * t + 1];
    int pair = v0 + v1;
    ls[t] = pair;
    __syncthreads();
#pragma unroll
    for (int d = 1; d < 256; d <<= 1) {
        int u = (t >= d) ? ls[t - d] : 0;
        __syncthreads();
        ls[t] += u;
        __syncthreads();
    }
    int excl = ls[t] - pair;
    lcur[2 * t] = excl;
    lcur[2 * t + 1] = excl + v0;
    int sg = seg0 + 2 * t;
    if (sg < M) off[sg] = base + excl;
    if (sg + 1 < M) off[sg + 1] = base + excl + v0;
    if (b == NBIN - 1 && t == 0) off[M] = twoE;
    __syncthreads();
    for (int k = t; k < cnt; k += 256) {
        unsigned r = rec[base + k];
        int pos = atomicAdd(&lcur[r >> 20], 1);
        csr[base + pos] = (int)(r & 0xFFFFFu);
    }
}

// ---------------- fused: per-node softmax-aggregate + combine + LN ----------------
// Fast path (len0,len1 <= 32, ~all nodes): half-wave per direction — lanes 0-31
// process 'in' edges, 32-63 process 'out' edges concurrently; compacted edge list
// (len0+len1) feeds ONE quarter-wave dot2 aggregation loop.
__global__ __launch_bounds__(256) void node_aggr_ln_k(const unsigned* __restrict__ hp_pk,
                                                      const unsigned* __restrict__ hs_pk,
                                                      const float* __restrict__ pA0, const float* __restrict__ pA1,
                                                      const float* __restrict__ pB0, const float* __restrict__ pB1,
                                                      const int* __restrict__ off, const int* __restrict__ csr,
                                                      const float* __restrict__ bias,
                                                      const float* __restrict__ gamma,
                                                      const float* __restrict__ beta,
                                                      float* __restrict__ out, int N) {
    __shared__ int sds[4][64];     // per-edge sender id
    __shared__ uint2 wts[4][64];   // per-edge f16 head weights: {pk(w0,w1), pk(w2,w3)}
    const int wave = threadIdx.x >> 6;
    const int lane = threadIdx.x & 63;
    const int n = blockIdx.x * 4 + wave;
    if (n >= N) return;
    const int l15 = lane & 15;
    const int q = lane >> 4;
    const unsigned wsel = (l15 & 4) ? 0x07060302u : 0x05040100u;  // pick f16 (h&1) of weight words
    const bool hlo = (l15 < 8);                                   // head < 2
    int* sdw = sds[wave];
    uint2* wtw = wts[wave];
    const char* hpb = (const char*)hp_pk;   // row stride 256 B
    const unsigned rowoff = (unsigned)l15 << 4;

    float acc[8];
#pragma unroll
    for (int k = 0; k < 8; ++k) acc[k] = 0.f;

    const int beg0 = off[n], end0 = off[n + 1];
    const int beg1 = off[N + n], end1 = off[N + n + 1];
    const int len0 = end0 - beg0, len1 = end1 - beg1;

    if (len0 <= 32 && len1 <= 32) {
        // ---- fused dual-direction softmax, half-wave each ----
        const int half = lane >> 5;
        const int hl = lane & 31;
        const int beg = half ? beg1 : beg0;
        const int len = half ? len1 : len0;
        const float* __restrict__ pp0 = half ? pB0 : pA0;
        const float* __restrict__ pp1 = half ? pB1 : pA1;
        float4 r1 = ((const float4*)pp1)[n];
        int sid = 0;
        float e0 = -INFINITY, e1 = -INFINITY, e2 = -INFINITY, e3 = -INFINITY;
        if (hl < len) {
            sid = csr[beg + hl];
            float4 r0 = ((const float4*)pp0)[sid];
            e0 = lrelu(r0.x + r1.x);
            e1 = lrelu(r0.y + r1.y);
            e2 = lrelu(r0.z + r1.z);
            e3 = lrelu(r0.w + r1.w);
        }
        float m0 = e0, m1 = e1, m2 = e2, m3 = e3;
        const bool small16 = (len0 <= 16 && len1 <= 16);
        if (small16) rmax4<16>(m0, m1, m2, m3);
        else         rmax4<32>(m0, m1, m2, m3);
        float w0 = 0.f, w1 = 0.f, w2 = 0.f, w3 = 0.f;
        if (hl < len) {
            w0 = __expf(e0 - m0); w1 = __expf(e1 - m1);
            w2 = __expf(e2 - m2); w3 = __expf(e3 - m3);
        }
        float s0 = w0, s1 = w1, s2 = w2, s3 = w3;
        if (small16) rsum4<16>(s0, s1, s2, s3);
        else         rsum4<32>(s0, s1, s2, s3);
        w0 *= 1.f / (s0 + EPS_SM);
        w1 *= 1.f / (s1 + EPS_SM);
        w2 *= 1.f / (s2 + EPS_SM);
        w3 *= 1.f / (s3 + EPS_SM);
        // compacted edge table: dir0 at [0,len0), dir1 at [len0, len0+len1); rest zero
        sdw[lane] = 0;
        wtw[lane] = make_uint2(0u, 0u);
        if (hl < len) {
            int pos = half ? len0 + hl : hl;
            sdw[pos] = sid;
            wtw[pos] = make_uint2(pkh(w0, w1), pkh(w2, w3));
        }
        aggr_pairs(len0 + len1, sdw, wtw, hpb, rowoff, q, hlo, wsel, acc);
    } else {
        // ---- rare fallback: sequential per-direction (any degree) ----
#pragma unroll
        for (int dir = 0; dir < 2; ++dir) {
            const int beg = (dir == 0) ? beg0 : beg1;
            const int end = (dir == 0) ? end0 : end1;
            const int len = end - beg;
            if (len == 0) continue;
            const float* __restrict__ p0 = (dir == 0) ? pA0 : pB0;
            const float* __restrict__ p1 = (dir == 0) ? pA1 : pB1;
            float4 r1 = ((const float4*)p1)[n];

            if (len <= 64) {
                int sid = 0;
                float e0 = -INFINITY, e1 = -INFINITY, e2 = -INFINITY, e3 = -INFINITY;
                if (lane < len) {
                    sid = csr[beg + lane];
                    float4 r0 = ((const float4*)p0)[sid];
                    e0 = lrelu(r0.x + r1.x);
                    e1 = lrelu(r0.y + r1.y);
                    e2 = lrelu(r0.z + r1.z);
                    e3 = lrelu(r0.w + r1.w);
                }
                float m0 = e0, m1 = e1, m2 = e2, m3 = e3;
                rmax4<64>(m0, m1, m2, m3);
                float w0 = 0.f, w1 = 0.f, w2 = 0.f, w3 = 0.f;
                if (lane < len) {
                    w0 = __expf(e0 - m0); w1 = __expf(e1 - m1);
                    w2 = __expf(e2 - m2); w3 = __expf(e3 - m3);
                }
                float s0 = w0, s1 = w1, s2 = w2, s3 = w3;
                rsum4<64>(s0, s1, s2, s3);
                w0 *= 1.f / (s0 + EPS_SM);
                w1 *= 1.f / (s1 + EPS_SM);
                w2 *= 1.f / (s2 + EPS_SM);
                w3 *= 1.f / (s3 + EPS_SM);
                sdw[lane] = sid;
                wtw[lane] = make_uint2(pkh(w0, w1), pkh(w2, w3));
                aggr_pairs(len, sdw, wtw, hpb, rowoff, q, hlo, wsel, acc);
            } else {
                float m0 = -INFINITY, m1 = -INFINITY, m2 = -INFINITY, m3 = -INFINITY;
                for (int base = beg; base < end; base += 64) {
                    int j = base + lane;
                    if (j < end) {
                        int sid = csr[j];
                        float4 r0 = ((const float4*)p0)[sid];
                        m0 = fmaxf(m0, lrelu(r0.x + r1.x));
                        m1 = fmaxf(m1, lrelu(r0.y + r1.y));
                        m2 = fmaxf(m2, lrelu(r0.z + r1.z));
                        m3 = fmaxf(m3, lrelu(r0.w + r1.w));
                    }
                }
                rmax4<64>(m0, m1, m2, m3);
                float s0 = 0.f, s1 = 0.f, s2 = 0.f, s3 = 0.f;
                for (int base = beg; base < end; base += 64) {
                    int j = base + lane;
                    if (j < end) {
                        int sid = csr[j];
                        float4 r0 = ((const float4*)p0)[sid];
                        s0 += __expf(lrelu(r0.x + r1.x) - m0);
                        s1 += __expf(lrelu(r0.y + r1.y) - m1);
                        s2 += __expf(lrelu(r0.z + r1.z) - m2);
                        s3 += __expf(lrelu(r0.w + r1.w) - m3);
                    }
                }
                rsum4<64>(s0, s1, s2, s3);
                const float is0 = 1.f / (s0 + EPS_SM);
                const float is1 = 1.f / (s1 + EPS_SM);
                const float is2 = 1.f / (s2 + EPS_SM);
                const float is3 = 1.f / (s3 + EPS_SM);
                for (int base = beg; base < end; base += 64) {
                    int cnt = min(64, end - base);
                    int sid = 0;
                    float w0 = 0.f, w1 = 0.f, w2 = 0.f, w3 = 0.f;
                    if (lane < cnt) {
                        sid = csr[base + lane];
                        float4 r0 = ((const float4*)p0)[sid];
                        w0 = __expf(lrelu(r0.x + r1.x) - m0) * is0;
                        w1 = __expf(lrelu(r0.y + r1.y) - m1) * is1;
                        w2 = __expf(lrelu(r0.z + r1.z) - m2) * is2;
                        w3 = __expf(lrelu(r0.w + r1.w) - m3) * is3;
                    }
                    sdw[lane] = sid;
                    wtw[lane] = make_uint2(pkh(w0, w1), pkh(w2, w3));
                    aggr_pairs(cnt, sdw, wtw, hpb, rowoff, q, hlo, wsel, acc);
                }
            }
        }
    }

    // merge quarter-wave partials (each quarter covered a disjoint edge subset)
#pragma unroll
    for (int s = 16; s < 64; s <<= 1) {
#pragma unroll
        for (int k = 0; k < 8; ++k) acc[k] += __shfl_xor(acc[k], s, 64);
    }

    // combine + LayerNorm (lane holds channels 8*l15..8*l15+7; duplicated across quarters)
    size_t bb = (size_t)n * DIM;
    uint4 hv = ((const uint4*)hs_pk)[(size_t)n * 16 + l15];
    float4 b0 = ((const float4*)bias)[2 * l15];
    float4 b1 = ((const float4*)bias)[2 * l15 + 1];
    float x0 = lo16(hv.x) + acc[0] + b0.x;
    float x1 = hi16(hv.x) + acc[1] + b0.y;
    float x2 = lo16(hv.y) + acc[2] + b0.z;
    float x3 = hi16(hv.y) + acc[3] + b0.w;
    float y0 = lo16(hv.z) + acc[4] + b1.x;
    float y1 = hi16(hv.z) + acc[5] + b1.y;
    float y2 = lo16(hv.w) + acc[6] + b1.z;
    float y3 = hi16(hv.w) + acc[7] + b1.w;
    float sum = x0 + x1 + x2 + x3 + y0 + y1 + y2 + y3;
    float sq = x0 * x0 + x1 * x1 + x2 * x2 + x3 * x3
             + y0 * y0 + y1 * y1 + y2 * y2 + y3 * y3;
#pragma unroll
    for (int m = 1; m < 64; m <<= 1) {
        sum += __shfl_xor(sum, m, 64);
        sq += __shfl_xor(sq, m, 64);
    }
    float mean = sum * (1.f / 512.f);          // each channel counted 4x
    float var = sq * (1.f / 512.f) - mean * mean;
    float inv = rsqrtf(var + EPS_LN);
    if (lane < 16) {
        float4 g0 = ((const float4*)gamma)[2 * l15];
        float4 g1 = ((const float4*)gamma)[2 * l15 + 1];
        float4 be0 = ((const float4*)beta)[2 * l15];
        float4 be1 = ((const float4*)beta)[2 * l15 + 1];
        float4 o0 = make_float4((x0 - mean) * inv * g0.x + be0.x,
                                (x1 - mean) * inv * g0.y + be0.y,
                                (x2 - mean) * inv * g0.z + be0.z,
                                (x3 - mean) * inv * g0.w + be0.w);
        float4 o1 = make_float4((y0 - mean) * inv * g1.x + be1.x,
                                (y1 - mean) * inv * g1.y + be1.y,
                                (y2 - mean) * inv * g1.z + be1.z,
                                (y3 - mean) * inv * g1.w + be1.w);
        ((float4*)(out + bb))[2 * l15] = o0;
        ((float4*)(out + bb))[2 * l15 + 1] = o1;
    }
}

extern "C" void kernel_launch(void* const* d_in, const int* in_sizes, int n_in,
                              void* d_out, int out_size, void* d_ws, size_t ws_size,
                              hipStream_t stream) {
    const float* h      = (const float*)d_in[0];
    const int*   ei     = (const int*)d_in[1];
    const float* W      = (const float*)d_in[2];
    const float* W_self = (const float*)d_in[3];
    const float* a_in   = (const float*)d_in[4];
    const float* a_out  = (const float*)d_in[5];
    const float* bias   = (const float*)d_in[6];
    const float* gamma  = (const float*)d_in[7];
    const float* beta   = (const float*)d_in[8];
    float* out = (float*)d_out;

    const int N = in_sizes[0] / DIM;
    const int E = in_sizes[1] / 2;
    const int M = 2 * N;
    const int NBIN = (M + (1 << SH1) - 1) >> SH1;
    const int twoE = 2 * E;

    // workspace layout
    float* ws = (float*)d_ws;
    size_t off_f = 0;
    unsigned* hs_pk = (unsigned*)(ws + off_f); off_f += (size_t)N * 64;   // f16 self-proj
    unsigned* hp_pk = (unsigned*)(ws + off_f); off_f += (size_t)N * 64;   // f16 W-proj
    float* pA0 = ws + off_f; off_f += (size_t)N * 4;
    float* pA1 = ws + off_f; off_f += (size_t)N * 4;
    float* pB0 = ws + off_f; off_f += (size_t)N * 4;
    float* pB1 = ws + off_f; off_f += (size_t)N * 4;
    int* ip = (int*)(ws + off_f);
    size_t off_i = 0;
    int* cntmat = ip + off_i; off_i += (size_t)NBIN * PB;
    int* blkoff = ip + off_i; off_i += (size_t)NBIN * PB;
    int* btot   = ip + off_i; off_i += NBIN;
    int* bbase  = ip + off_i; off_i += (size_t)NBIN + 1;
    int* off    = ip + off_i; off_i += (size_t)M + 1;
    unsigned* rec = (unsigned*)(ip + off_i); off_i += (size_t)twoE;
    int* csr    = ip + off_i; off_i += (size_t)twoE;
    _Float16* Bt = (_Float16*)(ip + off_i); off_i += (size_t)(BCOLS * 128) / 2;

    // ---- histogram + Bt build (merged) ----
    part1a_k<<<PB + BCOLS / 2, 256, 0, stream>>>(ei, cntmat, E, N, NBIN,
                                                 W, W_self, a_in, a_out, Bt);
    // ---- deterministic two-level CSR build ----
    scanB_k<<<NBIN, PB, 0, stream>>>(cntmat, blkoff, btot);
    scanC_k<<<1, 256, 0, stream>>>(btot, bbase, NBIN, twoE);
    part1b_k<<<PB, 256, 0, stream>>>(ei, bbase, blkoff, rec, E, N, NBIN);
    build2_k<<<NBIN, 256, 0, stream>>>(rec, bbase, off, csr, M, twoE, NBIN);

    // ---- MFMA projections + folded dots + f16 packs ----
    mfma_gemm_k<<<(N + 63) / 64, 256, 0, stream>>>(h, Bt, hs_pk, hp_pk,
                                                   pA0, pA1, pB0, pB1, N);

    // ---- fused aggregate + LN ----
    node_aggr_ln_k<<<(N + 3) / 4, 256, 0, stream>>>(hp_pk, hs_pk, pA0, pA1, pB0, pB1,
                                                    off, csr, bias, gamma, beta, out, N);
}

// Round 4
// 372.214 us; speedup vs baseline: 1.2322x; 1.0697x over previous
//
#include <hip/hip_runtime.h>
#include <math.h>

#define HEADS 4
#define HD 32
#define DIM 128
#define NEG_SLOPE 0.2f
#define EPS_SM 1e-8f
#define EPS_LN 1e-5f
#define SH1 9              // 512 segments per coarse bin; NBIN = ceil(2N/512) <= 512
#define PB 256             // partition blocks (full machine)
#define BCOLS 272          // 128 W + 128 W_self + 16 folded attention-dot cols

typedef _Float16 h2_t __attribute__((ext_vector_type(2)));
typedef _Float16 f16x8 __attribute__((ext_vector_type(8)));
typedef float f32x4 __attribute__((ext_vector_type(4)));

__device__ __forceinline__ float lrelu(float x) { return x > 0.f ? x : NEG_SLOPE * x; }
__device__ __forceinline__ unsigned pkh(float a, float b) {
    return __builtin_bit_cast(unsigned, __builtin_amdgcn_cvt_pkrtz(a, b));
}
__device__ __forceinline__ float dot2(unsigned a, unsigned b, float c) {
    return __builtin_amdgcn_fdot2(__builtin_bit_cast(h2_t, a), __builtin_bit_cast(h2_t, b), c, false);
}
__device__ __forceinline__ float lo16(unsigned u) { return (float)__builtin_bit_cast(h2_t, u)[0]; }
__device__ __forceinline__ float hi16(unsigned u) { return (float)__builtin_bit_cast(h2_t, u)[1]; }

template<int LIM> __device__ __forceinline__ void rmax4(float& a, float& b, float& c, float& d) {
#pragma unroll
    for (int s = 1; s < LIM; s <<= 1) {
        a = fmaxf(a, __shfl_xor(a, s, 64));
        b = fmaxf(b, __shfl_xor(b, s, 64));
        c = fmaxf(c, __shfl_xor(c, s, 64));
        d = fmaxf(d, __shfl_xor(d, s, 64));
    }
}
template<int LIM> __device__ __forceinline__ void rsum4(float& a, float& b, float& c, float& d) {
#pragma unroll
    for (int s = 1; s < LIM; s <<= 1) {
        a += __shfl_xor(a, s, 64);
        b += __shfl_xor(b, s, 64);
        c += __shfl_xor(c, s, 64);
        d += __shfl_xor(d, s, 64);
    }
}

__device__ __forceinline__ void dot8(uint4 u, uint4 v, unsigned wpk, float (&acc)[8]) {
    acc[0] = dot2(__builtin_amdgcn_perm(v.x, u.x, 0x05040100u), wpk, acc[0]);
    acc[1] = dot2(__builtin_amdgcn_perm(v.x, u.x, 0x07060302u), wpk, acc[1]);
    acc[2] = dot2(__builtin_amdgcn_perm(v.y, u.y, 0x05040100u), wpk, acc[2]);
    acc[3] = dot2(__builtin_amdgcn_perm(v.y, u.y, 0x07060302u), wpk, acc[3]);
    acc[4] = dot2(__builtin_amdgcn_perm(v.z, u.z, 0x05040100u), wpk, acc[4]);
    acc[5] = dot2(__builtin_amdgcn_perm(v.z, u.z, 0x07060302u), wpk, acc[5]);
    acc[6] = dot2(__builtin_amdgcn_perm(v.w, u.w, 0x05040100u), wpk, acc[6]);
    acc[7] = dot2(__builtin_amdgcn_perm(v.w, u.w, 0x07060302u), wpk, acc[7]);
}

// shared aggregation inner loop (fallback path): 8 edges (4 pairs) per iter
__device__ __forceinline__ void aggr_pairs(int cnt, const int* __restrict__ sdw,
                                           const uint2* __restrict__ wtw,
                                           const char* __restrict__ hpb,
                                           unsigned rowoff, int q, bool hlo, unsigned wsel,
                                           float (&acc)[8]) {
    const int npair = (cnt + 7) >> 3;
#pragma unroll 2
    for (int t = 0; t < npair; ++t) {
        int pi = 4 * t + q;
        uint2 sp = *(const uint2*)&sdw[2 * pi];
        uint4 wp = *(const uint4*)&wtw[2 * pi];
        uint4 u = *(const uint4*)(hpb + (((unsigned)sp.x << 8) + rowoff));
        uint4 v = *(const uint4*)(hpb + (((unsigned)sp.y << 8) + rowoff));
        unsigned wA = hlo ? wp.x : wp.y;
        unsigned wB = hlo ? wp.z : wp.w;
        unsigned wpk = __builtin_amdgcn_perm(wB, wA, wsel);
        dot8(u, v, wpk, acc);
    }
}

// ---------------- part1a (bin histogram) + folded cvtb (Bt build) ----------------
__global__ __launch_bounds__(256) void part1a_k(const int* __restrict__ ei, int* __restrict__ cntmat,
                                                int E, int N, int NBIN,
                                                const float* __restrict__ W,
                                                const float* __restrict__ V,
                                                const float* __restrict__ a_in,
                                                const float* __restrict__ a_out,
                                                _Float16* __restrict__ Bt) {
    __shared__ int lcnt[512];
    const int t = threadIdx.x;
    if (blockIdx.x >= PB) {
        int c = (blockIdx.x - PB) * 2 + (t >> 7);   // 0..BCOLS-1
        int k = t & 127;
        float v;
        if (c < 128) {
            v = W[k * 128 + c];
        } else if (c < 256) {
            v = V[k * 128 + (c - 128)];
        } else {
            int d = (c - 256) >> 2, hh = (c - 256) & 3;
            const float* a = (d < 2) ? a_in : a_out;
            int base = hh * 64 + (d & 1) * 32;
            float s = 0.f;
#pragma unroll
            for (int tt = 0; tt < 32; ++tt) s += W[k * 128 + 32 * hh + tt] * a[base + tt];
            v = s;
        }
        Bt[c * 128 + k] = (_Float16)v;
        return;
    }
    const int CH = (E + PB - 1) / PB;
    const int e0 = blockIdx.x * CH;
    const int e1 = min(e0 + CH, E);
    for (int i = t; i < 512; i += 256) lcnt[i] = 0;
    __syncthreads();
    for (int e = e0 + t; e < e1; e += 256) {
        int s = ei[e], d = ei[E + e];
        atomicAdd(&lcnt[d >> SH1], 1);
        atomicAdd(&lcnt[(N + s) >> SH1], 1);
    }
    __syncthreads();
    for (int i = t; i < NBIN; i += 256) cntmat[i * PB + blockIdx.x] = lcnt[i];
}

// ---------------- scans ----------------
__global__ __launch_bounds__(256) void scanB_k(const int* __restrict__ cntmat,
                                               int* __restrict__ blkoff, int* __restrict__ btot) {
    __shared__ int ls[PB];
    const int bin = blockIdx.x;
    const int t = threadIdx.x;
    int v = cntmat[bin * PB + t];
    ls[t] = v;
    __syncthreads();
#pragma unroll
    for (int d = 1; d < PB; d <<= 1) {
        int u = (t >= d) ? ls[t - d] : 0;
        __syncthreads();
        ls[t] += u;
        __syncthreads();
    }
    blkoff[bin * PB + t] = ls[t] - v;
    if (t == PB - 1) btot[bin] = ls[t];
}

__global__ __launch_bounds__(256) void scanC_k(const int* __restrict__ btot,
                                               int* __restrict__ bbase, int NBIN, int twoE) {
    __shared__ int ls[256];
    int t = threadIdx.x;
    int i0 = 2 * t, i1 = 2 * t + 1;
    int v0 = (i0 < NBIN) ? btot[i0] : 0;
    int v1 = (i1 < NBIN) ? btot[i1] : 0;
    int pair = v0 + v1;
    ls[t] = pair;
    __syncthreads();
#pragma unroll
    for (int d = 1; d < 256; d <<= 1) {
        int u = (t >= d) ? ls[t - d] : 0;
        __syncthreads();
        ls[t] += u;
        __syncthreads();
    }
    int excl = ls[t] - pair;
    if (i0 < NBIN) bbase[i0] = excl;
    if (i1 < NBIN) bbase[i1] = excl + v0;
    if (t == 0) bbase[NBIN] = twoE;
}

// ---------------- fused: part1b scatter (blocks 0..PB-1) + MFMA GEMM (rest) ----------------
// part1b: deterministic scatter into reserved runs.
// gemm: h(f32->f16) @ Bt^T; wave w owns rows 16w..16w+15; 17 col-tiles; K = 4x32.
//   D-frag: col = lane&15, row = (lane>>4)*4 + reg   [m89-verified]
__global__ __launch_bounds__(256) void p1b_gemm_k(const int* __restrict__ ei,
                                                  const int* __restrict__ bbase,
                                                  const int* __restrict__ blkoff,
                                                  unsigned* __restrict__ rec, int E, int N, int NBIN,
                                                  const float* __restrict__ h,
                                                  const _Float16* __restrict__ Bt,
                                                  unsigned* __restrict__ hs_pk,
                                                  unsigned* __restrict__ hp_pk,
                                                  float* __restrict__ pA0, float* __restrict__ pA1,
                                                  float* __restrict__ pB0, float* __restrict__ pB1) {
    __shared__ int gb[512];
    __shared__ int lcur[512];
    __shared__ _Float16 hs[64][128];    // W-proj repack
    __shared__ _Float16 hss[64][128];   // self-proj repack

    if (blockIdx.x < PB) {
        // ---- part1b scatter ----
        const int t = threadIdx.x;
        const int CH = (E + PB - 1) / PB;
        const int e0 = blockIdx.x * CH;
        const int e1 = min(e0 + CH, E);
        for (int i = t; i < 512; i += 256) lcur[i] = 0;
        for (int i = t; i < NBIN; i += 256) gb[i] = bbase[i] + blkoff[i * PB + blockIdx.x];
        __syncthreads();
        for (int e = e0 + t; e < e1; e += 256) {
            int s = ei[e], d = ei[E + e];
            int b1 = d >> SH1;
            int r1 = atomicAdd(&lcur[b1], 1);
            rec[gb[b1] + r1] = (unsigned)s | ((unsigned)(d & 511) << 20);
            int so = N + s;
            int b2 = so >> SH1;
            int r2 = atomicAdd(&lcur[b2], 1);
            rec[gb[b2] + r2] = (unsigned)d | ((unsigned)(so & 511) << 20);
        }
        return;
    }

    // ---- MFMA GEMM ----
    const int tid = threadIdx.x;
    const int w = tid >> 6, l = tid & 63;
    const int l15 = l & 15;
    const int kg = l >> 4;             // 0..3
    const int row0 = (blockIdx.x - PB) * 64;
    const int arow = row0 + 16 * w + l15;

    f32x4 acc[17];
#pragma unroll
    for (int j = 0; j < 17; ++j) {
        acc[j][0] = 0.f; acc[j][1] = 0.f; acc[j][2] = 0.f; acc[j][3] = 0.f;
    }

    const uint4* __restrict__ bt4 = (const uint4*)Bt;   // 16 uint4 per Bt row

#pragma unroll
    for (int kc = 0; kc < 4; ++kc) {
        union { unsigned u[4]; f16x8 v; } cv;
        if (arow < N) {
            float4 x0 = ((const float4*)h)[(size_t)arow * 32 + kc * 8 + kg * 2];
            float4 x1 = ((const float4*)h)[(size_t)arow * 32 + kc * 8 + kg * 2 + 1];
            cv.u[0] = pkh(x0.x, x0.y); cv.u[1] = pkh(x0.z, x0.w);
            cv.u[2] = pkh(x1.x, x1.y); cv.u[3] = pkh(x1.z, x1.w);
        } else {
            cv.u[0] = 0u; cv.u[1] = 0u; cv.u[2] = 0u; cv.u[3] = 0u;
        }
        f16x8 af = cv.v;
#pragma unroll
        for (int j = 0; j < 17; ++j) {
            int col = 16 * j + l15;
            union { uint4 q; f16x8 v; } bc;
            bc.q = bt4[col * 16 + kc * 4 + kg];
            acc[j] = __builtin_amdgcn_mfma_f32_16x16x32_f16(af, bc.v, acc[j], 0, 0, 0);
        }
    }

    // ---- epilogue: f16 repack through LDS ----
    const int r4 = kg * 4;             // D row offset within 16x16 tile
    const int dsel = l15 >> 2, hh = l15 & 3;
    float* __restrict__ pd = (dsel == 0) ? pA0 : (dsel == 1) ? pA1 : (dsel == 2) ? pB0 : pB1;
#pragma unroll
    for (int r = 0; r < 4; ++r) {
        int lr = 16 * w + r4 + r;
        int grow = row0 + lr;
#pragma unroll
        for (int j = 0; j < 8; ++j)
            hs[lr][16 * j + l15] = (_Float16)acc[j][r];
#pragma unroll
        for (int j = 8; j < 16; ++j)
            hss[lr][16 * (j - 8) + l15] = (_Float16)acc[j][r];
        if (grow < N) pd[grow * 4 + hh] = acc[16][r];
    }
    __syncthreads();
    const uint4* hsv = (const uint4*)&hs[0][0];     // 16 uint4 per row
    const uint4* hssv = (const uint4*)&hss[0][0];
#pragma unroll
    for (int p = 0; p < 4; ++p) {
        int chunk = tid + p * 256;                  // 0..1023 = 64 rows x 16 chunks
        int rrow = chunk >> 4, cg = chunk & 15;
        int grow = row0 + rrow;
        if (grow < N) {
            ((uint4*)hp_pk)[(size_t)grow * 16 + cg] = hsv[rrow * 16 + cg];
            ((uint4*)hs_pk)[(size_t)grow * 16 + cg] = hssv[rrow * 16 + cg];
        }
    }
}

__global__ __launch_bounds__(256) void build2_k(const unsigned* __restrict__ rec,
                                                const int* __restrict__ bbase,
                                                int* __restrict__ off, int* __restrict__ csr,
                                                int M, int twoE, int NBIN) {
    __shared__ int lcnt[512];
    __shared__ int lcur[512];
    __shared__ int ls[256];
    const int b = blockIdx.x;
    const int t = threadIdx.x;
    const int base = bbase[b];
    const int cnt = bbase[b + 1] - base;
    const int seg0 = b << SH1;
    for (int i = t; i < 512; i += 256) lcnt[i] = 0;
    __syncthreads();
    for (int k = t; k < cnt; k += 256) atomicAdd(&lcnt[rec[base + k] >> 20], 1);
    __syncthreads();
    int v0 = lcnt[2 * t], v1 = lcnt[2 * t + 1];
    int pair = v0 + v1;
    ls[t] = pair;
    __syncthreads();
#pragma unroll
    for (int d = 1; d < 256; d <<= 1) {
        int u = (t >= d) ? ls[t - d] : 0;
        __syncthreads();
        ls[t] += u;
        __syncthreads();
    }
    int excl = ls[t] - pair;
    lcur[2 * t] = excl;
    lcur[2 * t + 1] = excl + v0;
    int sg = seg0 + 2 * t;
    if (sg < M) off[sg] = base + excl;
    if (sg + 1 < M) off[sg + 1] = base + excl + v0;
    if (b == NBIN - 1 && t == 0) off[M] = twoE;
    __syncthreads();
    for (int k = t; k < cnt; k += 256) {
        unsigned r = rec[base + k];
        int pos = atomicAdd(&lcur[r >> 20], 1);
        csr[base + pos] = (int)(r & 0xFFFFFu);
    }
}

// ---------------- fused: per-node softmax-aggregate + combine + LN ----------------
// Fast path (len0,len1 <= 32): half-wave per direction; sender-row loads for the
// first two pair-iterations are issued BEFORE the softmax reductions (sdw table is
// softmax-independent), and the aggregation loop is a 2-slot load/compute ping-pong.
#define ROWLD(x) (*(const uint4*)(hpb + (((unsigned)(x) << 8) + rowoff)))
__global__ __launch_bounds__(256) void node_aggr_ln_k(const unsigned* __restrict__ hp_pk,
                                                      const unsigned* __restrict__ hs_pk,
                                                      const float* __restrict__ pA0, const float* __restrict__ pA1,
                                                      const float* __restrict__ pB0, const float* __restrict__ pB1,
                                                      const int* __restrict__ off, const int* __restrict__ csr,
                                                      const float* __restrict__ bias,
                                                      const float* __restrict__ gamma,
                                                      const float* __restrict__ beta,
                                                      float* __restrict__ out, int N) {
    __shared__ int sds[4][64];     // per-edge sender id
    __shared__ uint2 wts[4][64];   // per-edge f16 head weights: {pk(w0,w1), pk(w2,w3)}
    const int wave = threadIdx.x >> 6;
    const int lane = threadIdx.x & 63;
    const int n = blockIdx.x * 4 + wave;
    if (n >= N) return;
    const int l15 = lane & 15;
    const int q = lane >> 4;
    const unsigned wsel = (l15 & 4) ? 0x07060302u : 0x05040100u;  // pick f16 (h&1) of weight words
    const bool hlo = (l15 < 8);                                   // head < 2
    int* sdw = sds[wave];
    uint2* wtw = wts[wave];
    const char* hpb = (const char*)hp_pk;   // row stride 256 B
    const unsigned rowoff = (unsigned)l15 << 4;

    float acc[8];
#pragma unroll
    for (int k = 0; k < 8; ++k) acc[k] = 0.f;

    const int beg0 = off[n], end0 = off[n + 1];
    const int beg1 = off[N + n], end1 = off[N + n + 1];
    const int len0 = end0 - beg0, len1 = end1 - beg1;

    if (len0 <= 32 && len1 <= 32) {
        // ---- fused dual-direction softmax, half-wave each ----
        const int half = lane >> 5;
        const int hl = lane & 31;
        const int beg = half ? beg1 : beg0;
        const int len = half ? len1 : len0;
        const float* __restrict__ pp0 = half ? pB0 : pA0;
        const float* __restrict__ pp1 = half ? pB1 : pA1;
        float4 r1 = ((const float4*)pp1)[n];
        int sid = 0;
        float e0 = -INFINITY, e1 = -INFINITY, e2 = -INFINITY, e3 = -INFINITY;
        float4 r0 = make_float4(0.f, 0.f, 0.f, 0.f);
        if (hl < len) {
            sid = csr[beg + hl];
            r0 = ((const float4*)pp0)[sid];
        }
        // publish sender ids NOW (softmax-independent) and zero the weight table
        sdw[lane] = 0;
        wtw[lane] = make_uint2(0u, 0u);
        if (hl < len) sdw[half ? len0 + hl : hl] = sid;

        const int cnt = len0 + len1;
        const int npair = (cnt + 7) >> 3;
        // prefetch pair-iterations 0 and 1 (overlaps softmax below)
        uint4 u0 = make_uint4(0u, 0u, 0u, 0u), v0 = u0, u1 = u0, v1 = u0;
        if (npair > 0) {
            uint2 s = *(const uint2*)&sdw[2 * q];
            u0 = ROWLD(s.x); v0 = ROWLD(s.y);
        }
        if (npair > 1) {
            uint2 s = *(const uint2*)&sdw[2 * (4 + q)];
            u1 = ROWLD(s.x); v1 = ROWLD(s.y);
        }

        if (hl < len) {
            e0 = lrelu(r0.x + r1.x);
            e1 = lrelu(r0.y + r1.y);
            e2 = lrelu(r0.z + r1.z);
            e3 = lrelu(r0.w + r1.w);
        }
        float m0 = e0, m1 = e1, m2 = e2, m3 = e3;
        const bool small16 = (len0 <= 16 && len1 <= 16);
        if (small16) rmax4<16>(m0, m1, m2, m3);
        else         rmax4<32>(m0, m1, m2, m3);
        float w0 = 0.f, w1 = 0.f, w2 = 0.f, w3 = 0.f;
        if (hl < len) {
            w0 = __expf(e0 - m0); w1 = __expf(e1 - m1);
            w2 = __expf(e2 - m2); w3 = __expf(e3 - m3);
        }
        float s0 = w0, s1 = w1, s2 = w2, s3 = w3;
        if (small16) rsum4<16>(s0, s1, s2, s3);
        else         rsum4<32>(s0, s1, s2, s3);
        w0 *= 1.f / (s0 + EPS_SM);
        w1 *= 1.f / (s1 + EPS_SM);
        w2 *= 1.f / (s2 + EPS_SM);
        w3 *= 1.f / (s3 + EPS_SM);
        if (hl < len)
            wtw[half ? len0 + hl : hl] = make_uint2(pkh(w0, w1), pkh(w2, w3));

        // ---- 2-slot ping-pong aggregation ----
        for (int t = 0; t < npair; t += 2) {
            {
                uint4 wp = *(const uint4*)&wtw[2 * (4 * t + q)];
                unsigned wA = hlo ? wp.x : wp.y;
                unsigned wB = hlo ? wp.z : wp.w;
                unsigned wpk = __builtin_amdgcn_perm(wB, wA, wsel);
                dot8(u0, v0, wpk, acc);
            }
            if (t + 2 < npair) {
                uint2 s = *(const uint2*)&sdw[2 * (4 * (t + 2) + q)];
                u0 = ROWLD(s.x); v0 = ROWLD(s.y);
            }
            if (t + 1 < npair) {
                uint4 wp = *(const uint4*)&wtw[2 * (4 * (t + 1) + q)];
                unsigned wA = hlo ? wp.x : wp.y;
                unsigned wB = hlo ? wp.z : wp.w;
                unsigned wpk = __builtin_amdgcn_perm(wB, wA, wsel);
                dot8(u1, v1, wpk, acc);
                if (t + 3 < npair) {
                    uint2 s = *(const uint2*)&sdw[2 * (4 * (t + 3) + q)];
                    u1 = ROWLD(s.x); v1 = ROWLD(s.y);
                }
            }
        }
    } else {
        // ---- rare fallback: sequential per-direction (any degree) ----
#pragma unroll
        for (int dir = 0; dir < 2; ++dir) {
            const int beg = (dir == 0) ? beg0 : beg1;
            const int end = (dir == 0) ? end0 : end1;
            const int len = end - beg;
            if (len == 0) continue;
            const float* __restrict__ p0 = (dir == 0) ? pA0 : pB0;
            const float* __restrict__ p1 = (dir == 0) ? pA1 : pB1;
            float4 r1 = ((const float4*)p1)[n];

            if (len <= 64) {
                int sid = 0;
                float e0 = -INFINITY, e1 = -INFINITY, e2 = -INFINITY, e3 = -INFINITY;
                if (lane < len) {
                    sid = csr[beg + lane];
                    float4 r0 = ((const float4*)p0)[sid];
                    e0 = lrelu(r0.x + r1.x);
                    e1 = lrelu(r0.y + r1.y);
                    e2 = lrelu(r0.z + r1.z);
                    e3 = lrelu(r0.w + r1.w);
                }
                float m0 = e0, m1 = e1, m2 = e2, m3 = e3;
                rmax4<64>(m0, m1, m2, m3);
                float w0 = 0.f, w1 = 0.f, w2 = 0.f, w3 = 0.f;
                if (lane < len) {
                    w0 = __expf(e0 - m0); w1 = __expf(e1 - m1);
                    w2 = __expf(e2 - m2); w3 = __expf(e3 - m3);
                }
                float s0 = w0, s1 = w1, s2 = w2, s3 = w3;
                rsum4<64>(s0, s1, s2, s3);
                w0 *= 1.f / (s0 + EPS_SM);
                w1 *= 1.f / (s1 + EPS_SM);
                w2 *= 1.f / (s2 + EPS_SM);
                w3 *= 1.f / (s3 + EPS_SM);
                sdw[lane] = sid;
                wtw[lane] = make_uint2(pkh(w0, w1), pkh(w2, w3));
                aggr_pairs(len, sdw, wtw, hpb, rowoff, q, hlo, wsel, acc);
            } else {
                float m0 = -INFINITY, m1 = -INFINITY, m2 = -INFINITY, m3 = -INFINITY;
                for (int base = beg; base < end; base += 64) {
                    int j = base + lane;
                    if (j < end) {
                        int sid = csr[j];
                        float4 r0 = ((const float4*)p0)[sid];
                        m0 = fmaxf(m0, lrelu(r0.x + r1.x));
                        m1 = fmaxf(m1, lrelu(r0.y + r1.y));
                        m2 = fmaxf(m2, lrelu(r0.z + r1.z));
                        m3 = fmaxf(m3, lrelu(r0.w + r1.w));
                    }
                }
                rmax4<64>(m0, m1, m2, m3);
                float s0 = 0.f, s1 = 0.f, s2 = 0.f, s3 = 0.f;
                for (int base = beg; base < end; base += 64) {
                    int j = base + lane;
                    if (j < end) {
                        int sid = csr[j];
                        float4 r0 = ((const float4*)p0)[sid];
                        s0 += __expf(lrelu(r0.x + r1.x) - m0);
                        s1 += __expf(lrelu(r0.y + r1.y) - m1);
                        s2 += __expf(lrelu(r0.z + r1.z) - m2);
                        s3 += __expf(lrelu(r0.w + r1.w) - m3);
                    }
                }
                rsum4<64>(s0, s1, s2, s3);
                const float is0 = 1.f / (s0 + EPS_SM);
                const float is1 = 1.f / (s1 + EPS_SM);
                const float is2 = 1.f / (s2 + EPS_SM);
                const float is3 = 1.f / (s3 + EPS_SM);
                for (int base = beg; base < end; base += 64) {
                    int cnt = min(64, end - base);
                    int sid = 0;
                    float w0 = 0.f, w1 = 0.f, w2 = 0.f, w3 = 0.f;
                    if (lane < cnt) {
                        sid = csr[base + lane];
                        float4 r0 = ((const float4*)p0)[sid];
                        w0 = __expf(lrelu(r0.x + r1.x) - m0) * is0;
                        w1 = __expf(lrelu(r0.y + r1.y) - m1) * is1;
                        w2 = __expf(lrelu(r0.z + r1.z) - m2) * is2;
                        w3 = __expf(lrelu(r0.w + r1.w) - m3) * is3;
                    }
                    sdw[lane] = sid;
                    wtw[lane] = make_uint2(pkh(w0, w1), pkh(w2, w3));
                    aggr_pairs(cnt, sdw, wtw, hpb, rowoff, q, hlo, wsel, acc);
                }
            }
        }
    }

    // merge quarter-wave partials (each quarter covered a disjoint edge subset)
#pragma unroll
    for (int s = 16; s < 64; s <<= 1) {
#pragma unroll
        for (int k = 0; k < 8; ++k) acc[k] += __shfl_xor(acc[k], s, 64);
    }

    // combine + LayerNorm (lane holds channels 8*l15..8*l15+7; duplicated across quarters)
    size_t bb = (size_t)n * DIM;
    uint4 hv = ((const uint4*)hs_pk)[(size_t)n * 16 + l15];
    float4 b0 = ((const float4*)bias)[2 * l15];
    float4 b1 = ((const float4*)bias)[2 * l15 + 1];
    float x0 = lo16(hv.x) + acc[0] + b0.x;
    float x1 = hi16(hv.x) + acc[1] + b0.y;
    float x2 = lo16(hv.y) + acc[2] + b0.z;
    float x3 = hi16(hv.y) + acc[3] + b0.w;
    float y0 = lo16(hv.z) + acc[4] + b1.x;
    float y1 = hi16(hv.z) + acc[5] + b1.y;
    float y2 = lo16(hv.w) + acc[6] + b1.z;
    float y3 = hi16(hv.w) + acc[7] + b1.w;
    float sum = x0 + x1 + x2 + x3 + y0 + y1 + y2 + y3;
    float sq = x0 * x0 + x1 * x1 + x2 * x2 + x3 * x3
             + y0 * y0 + y1 * y1 + y2 * y2 + y3 * y3;
#pragma unroll
    for (int m = 1; m < 64; m <<= 1) {
        sum += __shfl_xor(sum, m, 64);
        sq += __shfl_xor(sq, m, 64);
    }
    float mean = sum * (1.f / 512.f);          // each channel counted 4x
    float var = sq * (1.f / 512.f) - mean * mean;
    float inv = rsqrtf(var + EPS_LN);
    if (lane < 16) {
        float4 g0 = ((const float4*)gamma)[2 * l15];
        float4 g1 = ((const float4*)gamma)[2 * l15 + 1];
        float4 be0 = ((const float4*)beta)[2 * l15];
        float4 be1 = ((const float4*)beta)[2 * l15 + 1];
        float4 o0 = make_float4((x0 - mean) * inv * g0.x + be0.x,
                                (x1 - mean) * inv * g0.y + be0.y,
                                (x2 - mean) * inv * g0.z + be0.z,
                                (x3 - mean) * inv * g0.w + be0.w);
        float4 o1 = make_float4((y0 - mean) * inv * g1.x + be1.x,
                                (y1 - mean) * inv * g1.y + be1.y,
                                (y2 - mean) * inv * g1.z + be1.z,
                                (y3 - mean) * inv * g1.w + be1.w);
        ((float4*)(out + bb))[2 * l15] = o0;
        ((float4*)(out + bb))[2 * l15 + 1] = o1;
    }
}

extern "C" void kernel_launch(void* const* d_in, const int* in_sizes, int n_in,
                              void* d_out, int out_size, void* d_ws, size_t ws_size,
                              hipStream_t stream) {
    const float* h      = (const float*)d_in[0];
    const int*   ei     = (const int*)d_in[1];
    const float* W      = (const float*)d_in[2];
    const float* W_self = (const float*)d_in[3];
    const float* a_in   = (const float*)d_in[4];
    const float* a_out  = (const float*)d_in[5];
    const float* bias   = (const float*)d_in[6];
    const float* gamma  = (const float*)d_in[7];
    const float* beta   = (const float*)d_in[8];
    float* out = (float*)d_out;

    const int N = in_sizes[0] / DIM;
    const int E = in_sizes[1] / 2;
    const int M = 2 * N;
    const int NBIN = (M + (1 << SH1) - 1) >> SH1;
    const int twoE = 2 * E;

    // workspace layout
    float* ws = (float*)d_ws;
    size_t off_f = 0;
    unsigned* hs_pk = (unsigned*)(ws + off_f); off_f += (size_t)N * 64;   // f16 self-proj
    unsigned* hp_pk = (unsigned*)(ws + off_f); off_f += (size_t)N * 64;   // f16 W-proj
    float* pA0 = ws + off_f; off_f += (size_t)N * 4;
    float* pA1 = ws + off_f; off_f += (size_t)N * 4;
    float* pB0 = ws + off_f; off_f += (size_t)N * 4;
    float* pB1 = ws + off_f; off_f += (size_t)N * 4;
    int* ip = (int*)(ws + off_f);
    size_t off_i = 0;
    int* cntmat = ip + off_i; off_i += (size_t)NBIN * PB;
    int* blkoff = ip + off_i; off_i += (size_t)NBIN * PB;
    int* btot   = ip + off_i; off_i += NBIN;
    int* bbase  = ip + off_i; off_i += (size_t)NBIN + 1;
    int* off    = ip + off_i; off_i += (size_t)M + 1;
    unsigned* rec = (unsigned*)(ip + off_i); off_i += (size_t)twoE;
    int* csr    = ip + off_i; off_i += (size_t)twoE;
    _Float16* Bt = (_Float16*)(ip + off_i); off_i += (size_t)(BCOLS * 128) / 2;

    const int GB = (N + 63) / 64;

    // ---- histogram + Bt build (merged) ----
    part1a_k<<<PB + BCOLS / 2, 256, 0, stream>>>(ei, cntmat, E, N, NBIN,
                                                 W, W_self, a_in, a_out, Bt);
    // ---- scans ----
    scanB_k<<<NBIN, PB, 0, stream>>>(cntmat, blkoff, btot);
    scanC_k<<<1, 256, 0, stream>>>(btot, bbase, NBIN, twoE);

    // ---- fused: CSR scatter (blocks 0..PB-1) + MFMA GEMM (remaining blocks) ----
    p1b_gemm_k<<<PB + GB, 256, 0, stream>>>(ei, bbase, blkoff, rec, E, N, NBIN,
                                            h, Bt, hs_pk, hp_pk, pA0, pA1, pB0, pB1);

    // ---- CSR finalize ----
    build2_k<<<NBIN, 256, 0, stream>>>(rec, bbase, off, csr, M, twoE, NBIN);

    // ---- fused aggregate + LN ----
    node_aggr_ln_k<<<(N + 3) / 4, 256, 0, stream>>>(hp_pk, hs_pk, pA0, pA1, pB0, pB1,
                                                    off, csr, bias, gamma, beta, out, N);
}